// Round 4
// baseline (290.348 us; speedup 1.0000x reference)
//
#include <hip/hip_runtime.h>
#include <hip/hip_bf16.h>
#include <math.h>

#define NN   4096
#define FEAT 512
#define DIM  64
#define KC   100
#define LL   3

// ---- workspace layout (float offsets). Total ~20MB.
#define OFF_DFLAT   0                          // [4096] adj row sums (atomic)
#define OFF_CHSUM   4096                       // [64]
#define OFF_CHSQ    4160                       // [64]
#define OFF_CTR     4224                       // [16] barrier/done counters (u32)
#define ZERO_FLOATS 4240                       // zeroed by xwk blocks 0..16
#define OFF_XW      4240                       // [4096*64] fp32
#define OFF_YPART   (OFF_XW + NN*DIM)          // 8 slices fp32
#define OFF_GPART   (OFF_YPART + 8*NN*DIM)     // [64*128*192]
#define OFF_Y0      (OFF_GPART + 64*128*192)   // [4096*64]
#define OFF_QKV     (OFF_Y0 + NN*DIM)          // [2*101*192] ping-pong
#define OFF_SS      (OFF_QKV + 2*101*192)      // [100*100]
#define OFF_DENP    (OFF_SS + KC*KC)           // [1024]
#define OFF_NUMP    (OFF_DENP + 1024)          // [1024]
#define OFF_SB16    (OFF_NUMP + 1024)          // [4096*128] bf16
#define OFF_STB16   (OFF_SB16 + NN*128/2)      // [128*4096] bf16
#define OFF_YNT16   (OFF_STB16 + NN*128/2)     // [64*4096] bf16
#define OFF_XWT16   (OFF_YNT16 + NN*DIM/2)     // [64*4096] bf16

typedef __attribute__((ext_vector_type(8))) short bfrag;   // 8 bf16 (4 VGPRs)
typedef __attribute__((ext_vector_type(4))) float ffrag;   // 4 fp32 acc

__device__ __forceinline__ unsigned short f2bf(float f) {
    union { float f; unsigned u; } v; v.f = f;
    return (unsigned short)((v.u + 0x7FFFu + ((v.u >> 16) & 1u)) >> 16);
}
__device__ __forceinline__ float bf2f(unsigned short u) {
    union { unsigned u; float f; } v; v.u = (unsigned)u << 16; return v.f;
}
__device__ __forceinline__ unsigned int pk2(float a, float b) {
    __hip_bfloat162 h = __float22bfloat162_rn(make_float2(a, b));
    return *(unsigned int*)&h;
}

__device__ __forceinline__ float wsum(float v) {
#pragma unroll
    for (int o = 32; o > 0; o >>= 1) v += __shfl_xor(v, o, 64);
    return v;
}
__device__ __forceinline__ float wmax(float v) {
#pragma unroll
    for (int o = 32; o > 0; o >>= 1) v = fmaxf(v, __shfl_xor(v, o, 64));
    return v;
}
__device__ __forceinline__ float hsum32(float v) {
#pragma unroll
    for (int o = 16; o > 0; o >>= 1) v += __shfl_xor(v, o, 64);
    return v;
}
__device__ __forceinline__ float hmax32(float v) {
#pragma unroll
    for (int o = 16; o > 0; o >>= 1) v = fmaxf(v, __shfl_xor(v, o, 64));
    return v;
}

// ---- device-scope sync primitives (inter-block, co-resident grid) ----
// RELAXED polling (round-1 fix, verified): ACQUIRE per poll emits buffer_inv
// per iteration -> L2 disabled device-wide. Poll relaxed, single acquire
// fence after exit.
__device__ __forceinline__ unsigned rlx_load(const unsigned* p) {
    return __hip_atomic_load(p, __ATOMIC_RELAXED, __HIP_MEMORY_SCOPE_AGENT);
}
__device__ __forceinline__ void rel_add(unsigned* p) {
    __hip_atomic_fetch_add(p, 1u, __ATOMIC_RELEASE, __HIP_MEMORY_SCOPE_AGENT);
}
template <int SLP>
__device__ __forceinline__ void wait_ge(const unsigned* c, unsigned tgt) {
    while (rlx_load(c) < tgt) __builtin_amdgcn_s_sleep(SLP);
    __builtin_amdgcn_fence(__ATOMIC_ACQUIRE, "agent");   // single buffer_inv
}
// Raw LDS-handoff barrier: waits only lgkmcnt (LDS ops), NOT vmcnt -- keeps
// prefetched global loads in flight across the barrier (T14). __syncthreads
// would drain vmcnt(0) (FIFO: loads drain too), defeating the prefetch.
__device__ __forceinline__ void bar() {
    asm volatile("s_waitcnt lgkmcnt(0)" ::: "memory");
    __builtin_amdgcn_s_barrier();
}
__device__ __forceinline__ void gbar(unsigned* c, unsigned tgt) {
    __syncthreads();             // FULL drain: publishes this block's global stores
    if (threadIdx.x == 0) {
        rel_add(c);
        wait_ge<4>(c, tgt);
    }
    bar();
}

// xw = x @ conv_w (fp32, K=512 full) -> xw fp32 + xwT bf16. grid 256 x 16 rows.
// Also zero-inits ws[0..ZERO_FLOATS) from blocks 0..16 (incl. barrier counters).
__global__ __launch_bounds__(256) void xwk(const float* __restrict__ x,
                                           const float* __restrict__ B,
                                           float* __restrict__ xw,
                                           unsigned short* __restrict__ xwT,
                                           float* __restrict__ zws) {
    __shared__ float a_sh[16 * 68];
    __shared__ float b_sh[64 * 68];
    __shared__ unsigned short tl[64 * 17];
    const int t = threadIdx.x, rb = blockIdx.x;
    if (rb < 17) {
        const int zi = rb * 256 + t;
        if (zi < ZERO_FLOATS) zws[zi] = 0.f;
    }
    const int r = t >> 4, cg = (t & 15) * 4;
    float4 acc = make_float4(0.f, 0.f, 0.f, 0.f);
    for (int kt = 0; kt < FEAT; kt += 64) {
        *(float4*)&a_sh[(t >> 4) * 68 + (t & 15) * 4] =
            *(const float4*)(x + (size_t)(rb * 16 + (t >> 4)) * FEAT + kt + (t & 15) * 4);
#pragma unroll
        for (int p = 0; p < 4; ++p) {
            const int idx = t + 256 * p;
            const int kr = idx >> 4, c4 = (idx & 15) * 4;
            *(float4*)&b_sh[kr * 68 + c4] = *(const float4*)(B + (size_t)(kt + kr) * DIM + c4);
        }
        __syncthreads();
#pragma unroll 8
        for (int k = 0; k < 64; ++k) {
            const float av = a_sh[r * 68 + k];
            const float4 bv = *(float4*)&b_sh[k * 68 + cg];
            acc.x += av * bv.x; acc.y += av * bv.y;
            acc.z += av * bv.z; acc.w += av * bv.w;
        }
        __syncthreads();
    }
    *(float4*)&xw[(size_t)(rb * 16 + r) * DIM + cg] = acc;
    tl[(cg + 0) * 17 + r] = f2bf(acc.x);
    tl[(cg + 1) * 17 + r] = f2bf(acc.y);
    tl[(cg + 2) * 17 + r] = f2bf(acc.z);
    tl[(cg + 3) * 17 + r] = f2bf(acc.w);
    __syncthreads();
    const int d = t >> 2, c = (t & 3) * 4;
    ushort4 o;
    o.x = tl[d * 17 + c + 0]; o.y = tl[d * 17 + c + 1];
    o.z = tl[d * 17 + c + 2]; o.w = tl[d * 17 + c + 3];
    *(ushort4*)(xwT + (size_t)d * NN + rb * 16 + c) = o;
}

// ypart[ksl] = adj_bf16 @ xwT^T, 32-row tiles, grid (128, 8).
__global__ __launch_bounds__(256) void gemmA(const float* __restrict__ adj,
                                             const unsigned short* __restrict__ xwT,
                                             float* __restrict__ ypart,
                                             float* __restrict__ dflat) {
    __shared__ __align__(16) unsigned short a_sh[32 * 72];
    __shared__ __align__(16) unsigned short b_sh[64 * 72];
    const int t  = threadIdx.x;
    const int rb = blockIdx.x;                 // 0..127
    const int k0 = blockIdx.y * 512;           // 8 k-slices
    const int w = t >> 6, lane = t & 63;
    const int m = lane & 15, q = lane >> 4;
    const int ih = w & 1, jh = w >> 1;         // row-half, col-half
    const int srow = t >> 3, sq = t & 7;       // A staging: 32 rows x 8 thr
    const int bn = t >> 2, bc = t & 3;         // B staging: 64 rows x 4 thr
    ffrag acc[2];
    acc[0] = (ffrag){0.f, 0.f, 0.f, 0.f};
    acc[1] = (ffrag){0.f, 0.f, 0.f, 0.f};
    float dacc = 0.f;
    const float* abase = adj + (size_t)(rb * 32 + srow) * NN + k0;
    const unsigned short* bbase = xwT + (size_t)bn * NN + k0;
    for (int kt = 0; kt < 512; kt += 64) {
#pragma unroll
        for (int k = 0; k < 2; ++k) {
            const int p = sq + 8 * k;          // float4 slot 0..15
            const float4 v = *(const float4*)(abase + kt + 4 * p);
            dacc += v.x + v.y + v.z + v.w;
            *(uint2*)(a_sh + srow * 72 + 4 * p) = make_uint2(pk2(v.x, v.y), pk2(v.z, v.w));
        }
#pragma unroll
        for (int k = 0; k < 2; ++k) {
            const int c2 = bc + 4 * k;         // bfrag slot 0..7
            *(bfrag*)(b_sh + bn * 72 + c2 * 8) = *(const bfrag*)(bbase + kt + c2 * 8);
        }
        __syncthreads();
#pragma unroll
        for (int ks = 0; ks < 2; ++ks) {
            const bfrag af = *(const bfrag*)(a_sh + (ih * 16 + m) * 72 + ks * 32 + q * 8);
#pragma unroll
            for (int jj = 0; jj < 2; ++jj) {
                const bfrag bf = *(const bfrag*)(b_sh + ((jh * 2 + jj) * 16 + m) * 72 + ks * 32 + q * 8);
                acc[jj] = __builtin_amdgcn_mfma_f32_16x16x32_bf16(af, bf, acc[jj], 0, 0, 0);
            }
        }
        __syncthreads();
    }
    float* op = ypart + (size_t)blockIdx.y * NN * DIM;
#pragma unroll
    for (int jj = 0; jj < 2; ++jj)
#pragma unroll
        for (int r = 0; r < 4; ++r)
            op[(size_t)(rb * 32 + ih * 16 + q * 4 + r) * DIM + jh * 32 + jj * 16 + m] = acc[jj][r];
    dacc += __shfl_down(dacc, 1, 64);
    dacc += __shfl_down(dacc, 2, 64);
    dacc += __shfl_down(dacc, 4, 64);
    if (sq == 0) atomicAdd(&dflat[rb * 32 + srow], dacc);
}

// y = sum(8 y_part) + xw + conv_b ; per-channel sum/sumsq
__global__ __launch_bounds__(256) void bnstat(const float* __restrict__ ypart,
                                              const float* __restrict__ xw,
                                              const float* __restrict__ conv_b,
                                              float* __restrict__ Y0,
                                              float* __restrict__ chsum,
                                              float* __restrict__ chsq) {
    __shared__ float ssum[64], ssq[64];
    const int t = threadIdx.x;
    if (t < 64) { ssum[t] = 0.f; ssq[t] = 0.f; }
    __syncthreads();
    const int tid = blockIdx.x * 256 + t;
    const size_t e = (size_t)tid * 4;
    const int c0 = (int)(e & 63);
    float4 v = *(const float4*)(xw + e);
#pragma unroll
    for (int s = 0; s < 8; ++s) {
        const float4 u = *(const float4*)(ypart + (size_t)s * NN * DIM + e);
        v.x += u.x; v.y += u.y; v.z += u.z; v.w += u.w;
    }
    const float4 b = *(const float4*)(conv_b + c0);
    v.x += b.x; v.y += b.y; v.z += b.z; v.w += b.w;
    *(float4*)(Y0 + e) = v;
    atomicAdd(&ssum[c0 + 0], v.x); atomicAdd(&ssum[c0 + 1], v.y);
    atomicAdd(&ssum[c0 + 2], v.z); atomicAdd(&ssum[c0 + 3], v.w);
    atomicAdd(&ssq[c0 + 0], v.x * v.x); atomicAdd(&ssq[c0 + 1], v.y * v.y);
    atomicAdd(&ssq[c0 + 2], v.z * v.z); atomicAdd(&ssq[c0 + 3], v.w * v.w);
    __syncthreads();
    if (t < 64) { atomicAdd(&chsum[t], ssum[t]); atomicAdd(&chsq[t], ssq[t]); }
}

// per-row: BN affine, L2 norm, softmax -> Sb16 + ST (fused transpose) + YnT; den partials
__global__ __launch_bounds__(256) void rowsk(const float* __restrict__ Y0,
                                             const float* __restrict__ bn_g,
                                             const float* __restrict__ bn_b,
                                             const float* __restrict__ chsum,
                                             const float* __restrict__ chsq,
                                             const float* __restrict__ pool_w,
                                             const float* __restrict__ pool_b,
                                             const float* __restrict__ dflat,
                                             unsigned short* __restrict__ YnT,
                                             unsigned short* __restrict__ Sb16,
                                             unsigned short* __restrict__ ST,
                                             float* __restrict__ denp) {
    __shared__ float scale_sh[64], shift_sh[64];
    __shared__ float yn_sh[4][64];
    __shared__ float4 pw4[16 * 104];   // pw4[dq*104+k] = pool_w[4dq..4dq+3][k]
    __shared__ unsigned short sb_sh[4][128];
    __shared__ float denw[4];
    const int t = threadIdx.x;
    if (t < 64) {
        const float mn  = chsum[t] * (1.f / 4096.f);
        const float var = chsq[t] * (1.f / 4096.f) - mn * mn;
        const float sc  = bn_g[t] * rsqrtf(var + 1e-5f);
        scale_sh[t] = sc;
        shift_sh[t] = bn_b[t] - mn * sc;
    }
    for (int idx = t; idx < 16 * KC; idx += 256) {
        const int dq = idx / KC, k = idx - dq * KC;
        pw4[dq * 104 + k] = make_float4(pool_w[(4 * dq + 0) * KC + k],
                                        pool_w[(4 * dq + 1) * KC + k],
                                        pool_w[(4 * dq + 2) * KC + k],
                                        pool_w[(4 * dq + 3) * KC + k]);
    }
    __syncthreads();
    const int w = t >> 6, lane = t & 63;
    const int row = blockIdx.x * 4 + w;
    float v = Y0[(size_t)row * 64 + lane] * scale_sh[lane] + shift_sh[lane];
    const float nrm = fmaxf(sqrtf(wsum(v * v)), 1e-12f);
    const float yn = v / nrm;
    yn_sh[w][lane] = yn;
    const bool v2 = (lane + 64) < KC;
    const int j2 = v2 ? (lane + 64) : 0;     // clamped (finite garbage, masked later)
    float L1 = pool_b[lane];
    float L2 = pool_b[j2];
    __syncthreads();
#pragma unroll
    for (int dq = 0; dq < 16; ++dq) {
        const float4 yv = *(const float4*)&yn_sh[w][4 * dq];
        const float4 w1 = pw4[dq * 104 + lane];
        L1 += yv.x * w1.x + yv.y * w1.y + yv.z * w1.z + yv.w * w1.w;
        const float4 w2 = pw4[dq * 104 + j2];
        L2 += yv.x * w2.x + yv.y * w2.y + yv.z * w2.z + yv.w * w2.w;
    }
    const float mx = wmax(fmaxf(L1, v2 ? L2 : -1e30f));
    const float e1 = expf(L1 - mx);
    const float e2 = v2 ? expf(L2 - mx) : 0.f;
    const float inv = 1.f / wsum(e1 + e2);
    const float s1 = e1 * inv, s2 = e2 * inv;
    const unsigned short b1 = f2bf(s1), b2 = f2bf(s2);
    Sb16[(size_t)row * 128 + lane] = b1;
    Sb16[(size_t)row * 128 + 64 + lane] = b2;   // zero for cols >= 100
    sb_sh[w][lane] = b1;
    sb_sh[w][64 + lane] = b2;
    const float c = wsum(s1 * s1 + s2 * s2);
    if (lane == 0) denw[w] = dflat[row] * c;
    __syncthreads();
    if (t < 64) {
        // YnT: 4 consecutive rows of column d as one 8B store
        ushort4 o;
        o.x = f2bf(yn_sh[0][t]); o.y = f2bf(yn_sh[1][t]);
        o.z = f2bf(yn_sh[2][t]); o.w = f2bf(yn_sh[3][t]);
        *(ushort4*)(YnT + (size_t)t * NN + blockIdx.x * 4) = o;
    } else if (t < 192) {
        // ST: 4 consecutive rows of S column c as one 8B store
        const int c2 = t - 64;
        ushort4 o;
        o.x = sb_sh[0][c2]; o.y = sb_sh[1][c2];
        o.z = sb_sh[2][c2]; o.w = sb_sh[3][c2];
        *(ushort4*)(ST + (size_t)c2 * NN + blockIdx.x * 4) = o;
    } else if (t == 192) {
        denp[blockIdx.x] = denw[0] + denw[1] + denw[2] + denw[3];
    }
}

// ============================================================================
// xform: fused {gram, gramred, transformer x3, final, spmmT} in one launch.
// grid 256 x 512 threads. Blocks 0..100: transformer (block b owns token b).
// Blocks 101..255: workers (first 64 do gram tiles, then all stripe spmm).
// T14 applied to the transformer: every weight chunk is issued to REGISTERS
// early (previous phase) and written to LDS late; intra-block barriers are
// raw s_barrier + lgkmcnt(0) so in-flight global loads survive the barrier.
// __syncthreads (vmcnt drain) only before release adds / gbar entry.
// ============================================================================
__global__ __launch_bounds__(512) void xform(
        const float* __restrict__ adj,
        const unsigned short* __restrict__ ST,
        const unsigned short* __restrict__ Sb16,
        const unsigned short* __restrict__ YnT,
        float* __restrict__ gpart,
        const float* __restrict__ cls,
        float* __restrict__ ssb,
        float* __restrict__ qkvb,
        const float* __restrict__ g1, const float* __restrict__ b1,
        const float* __restrict__ qw, const float* __restrict__ qb,
        const float* __restrict__ pw, const float* __restrict__ pb,
        const float* __restrict__ g2, const float* __restrict__ b2,
        const float* __restrict__ w1, const float* __restrict__ bb1,
        const float* __restrict__ w2, const float* __restrict__ bb2,
        const float* __restrict__ ng, const float* __restrict__ nb,
        const float* __restrict__ hw, const float* __restrict__ hb,
        const float* __restrict__ denp, float* __restrict__ nump,
        unsigned* __restrict__ ctr,
        float* __restrict__ out) {
    __shared__ __align__(16) float big[13332];   // K|V stage / weight chunks / MFMA stage
    __shared__ float scsh[8 * 104];              // scores / probs
    __shared__ __align__(16) float partf[1056];  // cross-group partials / reductions
    __shared__ float q_l[64], osh[64], h2sh[64], h1sh[64], toksh[64], gsh[256];
    __shared__ float redw8[8];
    float (*part)[132] = (float(*)[132])partf;
    const int t = threadIdx.x, b = blockIdx.x;

    if (b < 101) {
        // ================= transformer path =================
        // prefetch layer-0 qkv_w at kernel entry -- hides under the gram wait
        float4 rqkv[6];
        {
            const float4* s4 = (const float4*)qw;
#pragma unroll
            for (int p = 0; p < 6; ++p) rqkv[p] = s4[t + 512 * p];
        }
        // ---- phase G: own gram row -> token (LDS) + ss row ----
        if (b == 0) {
            if (t < 64) toksh[t] = cls[t];
        } else {
            if (t == 0) wait_ge<2>(&ctr[3], 64u);
            bar();
            const int row = b - 1;
            if (t < 384) {
                const int col = t % 192, sg = t / 192;
                float v = 0.f;
                const float* gp = gpart + (size_t)row * 192 + col + (size_t)sg * 32 * 24576;
                for (int s = 0; s < 32; ++s) v += gp[(size_t)s * 24576];
                partf[sg * 192 + col] = v;
            }
            bar();
            if (t < 192) {
                const float v = partf[t] + partf[192 + t];
                if (t < 64) toksh[t] = v;
                else if (t < 164) ssb[row * 100 + (t - 64)] = v;   // published by gbar(l=0)
            }
        }
        bar();
        // ---- LN1 for layer 0 ----
        if (t < 64) {
            const float x = toksh[t];
            const float m = wsum(x) * (1.f / 64.f);
            const float var = wsum(x * x) * (1.f / 64.f) - m * m;
            h1sh[t] = (x - m) * rsqrtf(var + 1e-6f) * g1[t] + b1[t];
        }
        bar();
        for (int l = 0; l < LL; ++l) {
            float* qk = qkvb + (size_t)(l & 1) * (101 * 192);   // ping-pong
            // ---- A: qkv_w regs -> LDS, QKV compute ----
#pragma unroll
            for (int p = 0; p < 6; ++p) ((float4*)big)[t + 512 * p] = rqkv[p];
            bar();
            if (t < 384) {
                const int o = t % 192, grp = t / 192;
                float a = 0.f;
#pragma unroll 8
                for (int e = grp * 32; e < grp * 32 + 32; ++e)
                    a += h1sh[e] * big[e * 192 + o];
                partf[grp * 192 + o] = a;
            }
            bar();
            if (t < 192)
                qk[b * 192 + t] = qb[l * 192 + t] + partf[t] + partf[192 + t];
            // ---- 101-block barrier: all tokens' QKV visible ----
            gbar(&ctr[l], 101u);
            // ---- B: issue group-1 prefetch (KV, own q, pw, w1-ch0) ----
            float4 rkv[7], rq, rpw[2], rw1a[4];
#pragma unroll
            for (int p = 0; p < 7; ++p) {
                const int idx = t + 512 * p;
                if (idx < 3232)
                    rkv[p] = *(const float4*)(qk + (idx >> 5) * 192 + 64 + (idx & 31) * 4);
            }
            if (t < 16) rq = *(const float4*)(qk + b * 192 + t * 4);
#pragma unroll
            for (int p = 0; p < 2; ++p)
                rpw[p] = ((const float4*)(pw + (size_t)l * 4096))[t + 512 * p];
#pragma unroll
            for (int p = 0; p < 4; ++p) {
                const int idx = t + 512 * p;
                rw1a[p] = *(const float4*)(w1 + (size_t)l * 16384 + (idx >> 5) * 256 + (idx & 31) * 4);
            }
            float t_old = 0.f;
            if (t < 64) t_old = toksh[t];
            // KV regs -> LDS
#pragma unroll
            for (int p = 0; p < 7; ++p) {
                const int idx = t + 512 * p;
                if (idx < 3232) {
                    const int k = idx >> 5, c = idx & 31;
                    *(float4*)&big[k * 132 + c * 4] = rkv[p];
                }
            }
            if (t < 16) *(float4*)&q_l[t * 4] = rq;
            bar();
            // ---- scores ----
            const float scale = 0.35355339059327373f;
#pragma unroll
            for (int p = 0; p < 2; ++p) {
                const int idx = t + 512 * p;
                if (idx < 808) {
                    const int h = idx / 101, k = idx - h * 101;
                    float s = 0.f;
#pragma unroll
                    for (int d = 0; d < 8; ++d)
                        s += q_l[h * 8 + d] * big[k * 132 + h * 8 + d];
                    scsh[h * 104 + k] = s * scale;
                }
            }
            bar();
            // ---- softmax per head ----
            if (t < 256) {
                const int w = t >> 6;
                const int h = w * 2 + ((t >> 5) & 1);   // head 0..7
                const int lft = t & 31;
                float v[4];
#pragma unroll
                for (int g = 0; g < 4; ++g) {
                    const int k = lft + 32 * g;
                    v[g] = (k < 101) ? scsh[h * 104 + k] : -1e30f;
                }
                float mm = fmaxf(fmaxf(v[0], v[1]), fmaxf(v[2], v[3]));
                mm = hmax32(mm);
                float s = 0.f;
#pragma unroll
                for (int g = 0; g < 4; ++g) { v[g] = expf(v[g] - mm); s += v[g]; }
                s = hsum32(s);
                const float inv = 1.f / s;
#pragma unroll
                for (int g = 0; g < 4; ++g) {
                    const int k = lft + 32 * g;
                    if (k < 101) scsh[h * 104 + k] = v[g] * inv;
                }
            }
            bar();
            // ---- O = P @ V : 8-way k-split ----
            {
                const int o = t & 63, grp = t >> 6;
                float po = 0.f;
                for (int k = grp; k < 101; k += 8)
                    po += scsh[(o >> 3) * 104 + k] * big[k * 132 + 64 + o];
                part[grp][o] = po;
            }
            bar();
            if (t < 64)
                osh[t] = part[0][t] + part[1][t] + part[2][t] + part[3][t]
                       + part[4][t] + part[5][t] + part[6][t] + part[7][t];
            // ---- issue group-2 prefetch (w1-ch1, w2 both chunks) ----
            float4 rw1b[4], rw2a[4], rw2b[4];
#pragma unroll
            for (int p = 0; p < 4; ++p) {
                const int idx = t + 512 * p;
                rw1b[p] = *(const float4*)(w1 + (size_t)l * 16384 + (idx >> 5) * 256 + 128 + (idx & 31) * 4);
                rw2a[p] = ((const float4*)(w2 + (size_t)l * 16384))[idx];
                rw2b[p] = ((const float4*)(w2 + (size_t)l * 16384 + 8192))[idx];
            }
            bar();
            // ---- C: proj + LN2 ----
#pragma unroll
            for (int p = 0; p < 2; ++p) ((float4*)big)[t + 512 * p] = rpw[p];
            bar();
            {
                const int o = t & 63, grp = t >> 6;
                float pp = 0.f;
#pragma unroll
                for (int e = grp * 8; e < grp * 8 + 8; ++e)
                    pp += osh[e] * big[e * 64 + o];
                part[grp][o] = pp;
            }
            bar();
            float t1 = 0.f;
            if (t < 64) {
                float pr = pb[l * 64 + t];
#pragma unroll
                for (int g = 0; g < 8; ++g) pr += part[g][t];
                t1 = t_old + pr;
                const float m = wsum(t1) * (1.f / 64.f);
                const float var = wsum(t1 * t1) * (1.f / 64.f) - m * m;
                h2sh[t] = (t1 - m) * rsqrtf(var + 1e-6f) * g2[l * 64 + t] + b2[l * 64 + t];
            }
            bar();
            // ---- D: fc1 (2 x 128-col chunks) + GELU ----
#pragma unroll
            for (int p = 0; p < 4; ++p) {
                const int idx = t + 512 * p;
                *(float4*)&big[(idx >> 5) * 128 + (idx & 31) * 4] = rw1a[p];
            }
            bar();
            {
                const int o = t & 127, grp = t >> 7;
                float pa = 0.f;
#pragma unroll
                for (int e = grp * 16; e < grp * 16 + 16; ++e)
                    pa += h2sh[e] * big[e * 128 + o];
                part[grp][o] = pa;
            }
            bar();
            if (t < 128) {
                float a = bb1[l * 256 + t]
                        + part[0][t] + part[1][t] + part[2][t] + part[3][t];
                gsh[t] = 0.5f * a * (1.f + erff(a * 0.70710678118654752f));
            }
            bar();
#pragma unroll
            for (int p = 0; p < 4; ++p) {
                const int idx = t + 512 * p;
                *(float4*)&big[(idx >> 5) * 128 + (idx & 31) * 4] = rw1b[p];
            }
            bar();
            {
                const int o = t & 127, grp = t >> 7;
                float pa = 0.f;
#pragma unroll
                for (int e = grp * 16; e < grp * 16 + 16; ++e)
                    pa += h2sh[e] * big[e * 128 + o];
                part[grp][o] = pa;
            }
            bar();
            if (t < 128) {
                float a = bb1[l * 256 + 128 + t]
                        + part[0][t] + part[1][t] + part[2][t] + part[3][t];
                gsh[128 + t] = 0.5f * a * (1.f + erff(a * 0.70710678118654752f));
            }
            bar();
            // ---- E: fc2 (2 x 128-row chunks) ----
            float a2p = 0.f;
#pragma unroll
            for (int p = 0; p < 4; ++p) ((float4*)big)[t + 512 * p] = rw2a[p];
            bar();
            {
                const int o = t & 63, grp = t >> 6;
#pragma unroll
                for (int er = grp * 16; er < grp * 16 + 16; ++er)
                    a2p += gsh[er] * big[er * 64 + o];
            }
            bar();
#pragma unroll
            for (int p = 0; p < 4; ++p) ((float4*)big)[t + 512 * p] = rw2b[p];
            bar();
            {
                const int o = t & 63, grp = t >> 6;
#pragma unroll
                for (int er = grp * 16; er < grp * 16 + 16; ++er)
                    a2p += gsh[128 + er] * big[er * 64 + o];
            }
            // ---- issue next-layer qkv_w prefetch (hides under epilogue) ----
            if (l < 2) {
                const float4* s4 = (const float4*)(qw + (size_t)(l + 1) * 12288);
#pragma unroll
                for (int p = 0; p < 6; ++p) rqkv[p] = s4[t + 512 * p];
            }
            bar();
            {
                const int o = t & 63, grp = t >> 6;
                part[grp][o] = a2p;
            }
            bar();
            if (t < 64) {
                float a2 = bb2[l * 64 + t];
#pragma unroll
                for (int g = 0; g < 8; ++g) a2 += part[g][t];
                const float tn = t1 + a2;
                toksh[t] = tn;
                if (l < 2) {
                    const float m = wsum(tn) * (1.f / 64.f);
                    const float var = wsum(tn * tn) * (1.f / 64.f) - m * m;
                    h1sh[t] = (tn - m) * rsqrtf(var + 1e-6f) * g1[(l + 1) * 64 + t]
                              + b1[(l + 1) * 64 + t];
                }
            }
            bar();
        }
        // ---- final phase (block 0 only): LN + head + losses ----
        if (b == 0) {
            if (t < 64) {
                const float x = toksh[t];
                const float m = wsum(x) * (1.f / 64.f);
                const float var = wsum(x * x) * (1.f / 64.f) - m * m;
                h1sh[t] = (x - m) * rsqrtf(var + 1e-6f) * ng[t] + nb[t];
            }
            if (t == 0) wait_ge<8>(&ctr[4], 155u);
            __syncthreads();
            float* red = partf;
            red[t] = denp[t] + denp[t + 512];
            __syncthreads();
            for (int s = 256; s > 0; s >>= 1) { if (t < s) red[t] += red[t + s]; __syncthreads(); }
            if (t == 0) q_l[0] = red[0];
            __syncthreads();
            red[t] = nump[t] + nump[t + 512];
            __syncthreads();
            for (int s = 256; s > 0; s >>= 1) { if (t < s) red[t] += red[t + s]; __syncthreads(); }
            if (t == 0) q_l[1] = red[0];
            __syncthreads();
            if (t < 2) {
                float a = hb[t];
                for (int d = 0; d < 64; ++d) a += h1sh[d] * hw[d * 2 + t];
                out[t] = a;
            }
            if (t == 2) out[2] = -(q_l[1] / q_l[0]);
            float s1 = 0.f;
            for (int idx = t; idx < KC * KC; idx += 512) { const float v = ssb[idx]; s1 += v * v; }
            __syncthreads();
            red[t] = s1;
            __syncthreads();
            for (int s = 256; s > 0; s >>= 1) { if (t < s) red[t] += red[t + s]; __syncthreads(); }
            if (t == 0) q_l[2] = sqrtf(red[0]);
            __syncthreads();
            const float inv = 1.f / q_l[2];
            float s2 = 0.f;
            for (int idx = t; idx < KC * KC; idx += 512) {
                float v = ssb[idx] * inv;
                if (idx % 101 == 0) v -= 0.1f;   // diag: I/||I||_F = I/10
                s2 += v * v;
            }
            __syncthreads();
            red[t] = s2;
            __syncthreads();
            for (int s = 256; s > 0; s >>= 1) { if (t < s) red[t] += red[t + s]; __syncthreads(); }
            if (t == 0) out[3] = sqrtf(red[0]);
        }
    } else {
        // ================= worker path =================
        const int wb = b - 101;
        const int w = t >> 6, lane = t & 63;
        const int m = lane & 15, q = lane >> 4;
        if (wb < 64) {
            // ---- gram tile wb: C[128][192] partial for k-slice [wb*64, wb*64+64) ----
            unsigned short* a_sh = (unsigned short*)big;               // 128*72
            unsigned short* b_sh = (unsigned short*)big + 128 * 72;    // 192*72
            const int k0 = wb * 64;
            const int n0 = t >> 3, c8 = (t & 7) * 8;
#pragma unroll
            for (int p = 0; p < 2; ++p) {
                const int n = n0 + 64 * p;
                *(bfrag*)(a_sh + n * 72 + c8) = *(const bfrag*)(ST + (size_t)n * NN + k0 + c8);
            }
#pragma unroll
            for (int p = 0; p < 3; ++p) {
                const int n = n0 + 64 * p;
                const unsigned short* src = (n < 64) ? (YnT + (size_t)n * NN + k0 + c8)
                                                     : (ST + (size_t)(n - 64) * NN + k0 + c8);
                *(bfrag*)(b_sh + n * 72 + c8) = *(const bfrag*)src;
            }
            __syncthreads();
            ffrag acc[12];
#pragma unroll
            for (int j = 0; j < 12; ++j) acc[j] = (ffrag){0.f, 0.f, 0.f, 0.f};
#pragma unroll
            for (int ks = 0; ks < 2; ++ks) {
                const bfrag af = *(const bfrag*)(a_sh + (w * 16 + m) * 72 + ks * 32 + q * 8);
#pragma unroll
                for (int j = 0; j < 12; ++j) {
                    const bfrag bf = *(const bfrag*)(b_sh + (j * 16 + m) * 72 + ks * 32 + q * 8);
                    acc[j] = __builtin_amdgcn_mfma_f32_16x16x32_bf16(af, bf, acc[j], 0, 0, 0);
                }
            }
            float* op = gpart + (size_t)wb * 128 * 192;
#pragma unroll
            for (int j = 0; j < 12; ++j)
#pragma unroll
                for (int r = 0; r < 4; ++r)
                    op[(size_t)(w * 16 + q * 4 + r) * 192 + j * 16 + m] = acc[j][r];
            __syncthreads();                       // drains all gpart stores (vmcnt)
            if (t == 0) rel_add(&ctr[3]);          // release publishes them
        }
        // ---- spmm tiles: nump[tile] = sum(S .* (adj @ S)) over 32-row x 512-k tile ----
        unsigned short* a_sh = (unsigned short*)big;             // 32*72
        unsigned short* s_sh = (unsigned short*)big + 32 * 72;   // 128*72
        const int rh = w & 1, ch = w >> 1;
        const int srow = t >> 4, sq4 = (t & 15) * 4;
        const int sn = t >> 2, scq = t & 3;
        for (int tile = wb; tile < 1024; tile += 155) {
            const int rb = tile & 127;
            const int k0 = (tile >> 7) * 512;
            ffrag acc[2];
            acc[0] = (ffrag){0.f, 0.f, 0.f, 0.f};
            acc[1] = (ffrag){0.f, 0.f, 0.f, 0.f};
            const float* abase = adj + (size_t)(rb * 32 + srow) * NN + k0;
            const unsigned short* sbase = ST + (size_t)sn * NN + k0;
            for (int kt = 0; kt < 512; kt += 64) {
                {
                    const float4 v = *(const float4*)(abase + kt + sq4);
                    *(uint2*)(a_sh + srow * 72 + sq4) = make_uint2(pk2(v.x, v.y), pk2(v.z, v.w));
                }
#pragma unroll
                for (int k = 0; k < 2; ++k) {
                    const int c2 = scq + 4 * k;
                    *(bfrag*)(s_sh + sn * 72 + c2 * 8) = *(const bfrag*)(sbase + kt + c2 * 8);
                }
                __syncthreads();
#pragma unroll
                for (int ks = 0; ks < 2; ++ks) {
                    const bfrag af = *(const bfrag*)(a_sh + (rh * 16 + m) * 72 + ks * 32 + q * 8);
#pragma unroll
                    for (int j = 0; j < 2; ++j) {
                        const bfrag bf = *(const bfrag*)(s_sh + ((ch * 2 + j) * 16 + m) * 72 + ks * 32 + q * 8);
                        acc[j] = __builtin_amdgcn_mfma_f32_16x16x32_bf16(af, bf, acc[j], 0, 0, 0);
                    }
                }
                __syncthreads();
            }
            float local = 0.f;
#pragma unroll
            for (int j = 0; j < 2; ++j)
#pragma unroll
                for (int r = 0; r < 4; ++r) {
                    const int row = rb * 32 + rh * 16 + q * 4 + r;
                    const int col = ch * 32 + j * 16 + m;
                    local += acc[j][r] * bf2f(Sb16[(size_t)row * 128 + col]);
                }
            local = wsum(local);
            if (lane == 0) redw8[w] = local;
            __syncthreads();
            if (t == 0) {
                float s = 0.f;
#pragma unroll
                for (int k = 0; k < 8; ++k) s += redw8[k];
                nump[(tile >> 7) * 128 + rb] = s;
            }
            __syncthreads();
        }
        __syncthreads();                           // drains nump stores
        if (t == 0) rel_add(&ctr[4]);              // release publishes them
    }
}

extern "C" void kernel_launch(void* const* d_in, const int* in_sizes, int n_in,
                              void* d_out, int out_size, void* d_ws, size_t ws_size,
                              hipStream_t stream) {
    (void)in_sizes; (void)n_in; (void)out_size; (void)ws_size;
    const float* x      = (const float*)d_in[0];
    const float* adj    = (const float*)d_in[1];
    const float* conv_w = (const float*)d_in[2];
    const float* conv_b = (const float*)d_in[3];
    const float* bn_g   = (const float*)d_in[4];
    const float* bn_b   = (const float*)d_in[5];
    const float* pool_w = (const float*)d_in[6];
    const float* pool_b = (const float*)d_in[7];
    const float* cls    = (const float*)d_in[8];
    const float* ln1_g  = (const float*)d_in[9];
    const float* ln1_b  = (const float*)d_in[10];
    const float* qkv_w  = (const float*)d_in[11];
    const float* qkv_b  = (const float*)d_in[12];
    const float* proj_w = (const float*)d_in[13];
    const float* proj_b = (const float*)d_in[14];
    const float* ln2_g  = (const float*)d_in[15];
    const float* ln2_b  = (const float*)d_in[16];
    const float* fc1_w  = (const float*)d_in[17];
    const float* fc1_b  = (const float*)d_in[18];
    const float* fc2_w  = (const float*)d_in[19];
    const float* fc2_b  = (const float*)d_in[20];
    const float* norm_g = (const float*)d_in[21];
    const float* norm_b = (const float*)d_in[22];
    const float* head_w = (const float*)d_in[23];
    const float* head_b = (const float*)d_in[24];
    float* ws  = (float*)d_ws;
    float* out = (float*)d_out;
    unsigned short* Sb16  = (unsigned short*)(ws + OFF_SB16);
    unsigned short* STb16 = (unsigned short*)(ws + OFF_STB16);
    unsigned short* YnT16 = (unsigned short*)(ws + OFF_YNT16);
    unsigned short* xwT16 = (unsigned short*)(ws + OFF_XWT16);

    // xw = x @ conv_w (fused zero-init of accumulator region + sync counters)
    xwk<<<256, 256, 0, stream>>>(x, conv_w, ws + OFF_XW, xwT16, ws);
    // y_part = adj @ xw via bf16 MFMA (+ dflat row sums)
    gemmA<<<dim3(128, 8), 256, 0, stream>>>(adj, xwT16, ws + OFF_YPART, ws + OFF_DFLAT);
    bnstat<<<256, 256, 0, stream>>>(ws + OFF_YPART, ws + OFF_XW, conv_b,
                                    ws + OFF_Y0, ws + OFF_CHSUM, ws + OFF_CHSQ);
    rowsk<<<1024, 256, 0, stream>>>(ws + OFF_Y0, bn_g, bn_b, ws + OFF_CHSUM, ws + OFF_CHSQ,
                                    pool_w, pool_b, ws + OFF_DFLAT,
                                    YnT16, Sb16, STb16, ws + OFF_DENP);
    // fused gram + gramred + transformer + final + overlapped spmm
    xform<<<256, 512, 0, stream>>>(adj, STb16, Sb16, YnT16, ws + OFF_GPART, cls,
                                   ws + OFF_SS, ws + OFF_QKV,
                                   ln1_g, ln1_b, qkv_w, qkv_b, proj_w, proj_b,
                                   ln2_g, ln2_b, fc1_w, fc1_b, fc2_w, fc2_b,
                                   norm_g, norm_b, head_w, head_b,
                                   ws + OFF_DENP, ws + OFF_NUMP,
                                   (unsigned*)(ws + OFF_CTR), out);
}

// Round 6
// 281.091 us; speedup vs baseline: 1.0329x; 1.0329x over previous
//
#include <hip/hip_runtime.h>
#include <hip/hip_bf16.h>
#include <math.h>

#define NN   4096
#define FEAT 512
#define DIM  64
#define KC   100
#define LL   3

// ---- workspace layout (float offsets). Total ~20MB.
#define OFF_DFLAT   0                          // [4096] adj row sums (atomic)
#define OFF_CHSUM   4096                       // [64]
#define OFF_CHSQ    4160                       // [64]
#define OFF_CTR     4224                       // [16] barrier/done counters (u32)
#define ZERO_FLOATS 4240                       // zeroed by xwk blocks 0..16
#define OFF_XW      4240                       // [4096*64] fp32
#define OFF_YPART   (OFF_XW + NN*DIM)          // 8 slices fp32
#define OFF_GPART   (OFF_YPART + 8*NN*DIM)     // [64*128*192]
#define OFF_Y0      (OFF_GPART + 64*128*192)   // [4096*64]
#define OFF_QKV     (OFF_Y0 + NN*DIM)          // [2*101*192] ping-pong
#define OFF_SS      (OFF_QKV + 2*101*192)      // [100*100]
#define OFF_DENP    (OFF_SS + KC*KC)           // [1024]
#define OFF_NUMP    (OFF_DENP + 1024)          // [1024]
#define OFF_SB16    (OFF_NUMP + 1024)          // [4096*128] bf16
#define OFF_STB16   (OFF_SB16 + NN*128/2)      // [128*4096] bf16
#define OFF_YNT16   (OFF_STB16 + NN*128/2)     // [64*4096] bf16
#define OFF_XWT16   (OFF_YNT16 + NN*DIM/2)     // [64*4096] bf16

typedef __attribute__((ext_vector_type(8))) short bfrag;   // 8 bf16 (4 VGPRs)
typedef __attribute__((ext_vector_type(4))) float ffrag;   // 4 fp32 acc

__device__ __forceinline__ unsigned short f2bf(float f) {
    union { float f; unsigned u; } v; v.f = f;
    return (unsigned short)((v.u + 0x7FFFu + ((v.u >> 16) & 1u)) >> 16);
}
__device__ __forceinline__ float bf2f(unsigned short u) {
    union { unsigned u; float f; } v; v.u = (unsigned)u << 16; return v.f;
}
__device__ __forceinline__ unsigned int pk2(float a, float b) {
    __hip_bfloat162 h = __float22bfloat162_rn(make_float2(a, b));
    return *(unsigned int*)&h;
}

__device__ __forceinline__ float wsum(float v) {
#pragma unroll
    for (int o = 32; o > 0; o >>= 1) v += __shfl_xor(v, o, 64);
    return v;
}
__device__ __forceinline__ float wmax(float v) {
#pragma unroll
    for (int o = 32; o > 0; o >>= 1) v = fmaxf(v, __shfl_xor(v, o, 64));
    return v;
}
__device__ __forceinline__ float hsum32(float v) {
#pragma unroll
    for (int o = 16; o > 0; o >>= 1) v += __shfl_xor(v, o, 64);
    return v;
}
__device__ __forceinline__ float hmax32(float v) {
#pragma unroll
    for (int o = 16; o > 0; o >>= 1) v = fmaxf(v, __shfl_xor(v, o, 64));
    return v;
}

// ---- device-scope sync primitives (inter-block, co-resident grid) ----
// RELAXED polling (round-1 fix): ACQUIRE per poll emits buffer_inv per
// iteration -> L2 disabled device-wide. Poll relaxed, single acquire fence.
// ROUND-6 FIX: buffer_inv is vmcnt-tracked. The fence must be DRAINED
// (s_waitcnt vmcnt(0)) before the polling wave enters s_barrier, else other
// waves resume and read stale L2 lines (from a previous graph replay) before
// the invalidate lands. This was the round-5 post-timing divergence.
__device__ __forceinline__ unsigned rlx_load(const unsigned* p) {
    return __hip_atomic_load(p, __ATOMIC_RELAXED, __HIP_MEMORY_SCOPE_AGENT);
}
__device__ __forceinline__ void rel_add(unsigned* p) {
    __hip_atomic_fetch_add(p, 1u, __ATOMIC_RELEASE, __HIP_MEMORY_SCOPE_AGENT);
}
template <int SLP>
__device__ __forceinline__ void wait_ge(const unsigned* c, unsigned tgt) {
    while (rlx_load(c) < tgt) __builtin_amdgcn_s_sleep(SLP);
    __builtin_amdgcn_fence(__ATOMIC_ACQUIRE, "agent");   // buffer_inv
    asm volatile("s_waitcnt vmcnt(0)" ::: "memory");     // DRAIN the inv
}
// Raw LDS-handoff barrier: waits only lgkmcnt (LDS ops), NOT vmcnt -- keeps
// prefetched global loads in flight across the barrier (T14).
__device__ __forceinline__ void bar() {
    asm volatile("s_waitcnt lgkmcnt(0)" ::: "memory");
    __builtin_amdgcn_s_barrier();
}
__device__ __forceinline__ void gbar(unsigned* c, unsigned tgt) {
    __syncthreads();             // FULL drain: publishes this block's global stores
    if (threadIdx.x == 0) {
        rel_add(c);
        wait_ge<4>(c, tgt);      // returns with inv completed
    }
    bar();
}

// xw = x @ conv_w (fp32, K=512 full) -> xw fp32 + xwT bf16. grid 256 x 16 rows.
// Also zero-inits ws[0..ZERO_FLOATS) from blocks 0..16 (incl. barrier counters).
__global__ __launch_bounds__(256) void xwk(const float* __restrict__ x,
                                           const float* __restrict__ B,
                                           float* __restrict__ xw,
                                           unsigned short* __restrict__ xwT,
                                           float* __restrict__ zws) {
    __shared__ float a_sh[16 * 68];
    __shared__ float b_sh[64 * 68];
    __shared__ unsigned short tl[64 * 17];
    const int t = threadIdx.x, rb = blockIdx.x;
    if (rb < 17) {
        const int zi = rb * 256 + t;
        if (zi < ZERO_FLOATS) zws[zi] = 0.f;
    }
    const int r = t >> 4, cg = (t & 15) * 4;
    float4 acc = make_float4(0.f, 0.f, 0.f, 0.f);
    for (int kt = 0; kt < FEAT; kt += 64) {
        *(float4*)&a_sh[(t >> 4) * 68 + (t & 15) * 4] =
            *(const float4*)(x + (size_t)(rb * 16 + (t >> 4)) * FEAT + kt + (t & 15) * 4);
#pragma unroll
        for (int p = 0; p < 4; ++p) {
            const int idx = t + 256 * p;
            const int kr = idx >> 4, c4 = (idx & 15) * 4;
            *(float4*)&b_sh[kr * 68 + c4] = *(const float4*)(B + (size_t)(kt + kr) * DIM + c4);
        }
        __syncthreads();
#pragma unroll 8
        for (int k = 0; k < 64; ++k) {
            const float av = a_sh[r * 68 + k];
            const float4 bv = *(float4*)&b_sh[k * 68 + cg];
            acc.x += av * bv.x; acc.y += av * bv.y;
            acc.z += av * bv.z; acc.w += av * bv.w;
        }
        __syncthreads();
    }
    *(float4*)&xw[(size_t)(rb * 16 + r) * DIM + cg] = acc;
    tl[(cg + 0) * 17 + r] = f2bf(acc.x);
    tl[(cg + 1) * 17 + r] = f2bf(acc.y);
    tl[(cg + 2) * 17 + r] = f2bf(acc.z);
    tl[(cg + 3) * 17 + r] = f2bf(acc.w);
    __syncthreads();
    const int d = t >> 2, c = (t & 3) * 4;
    ushort4 o;
    o.x = tl[d * 17 + c + 0]; o.y = tl[d * 17 + c + 1];
    o.z = tl[d * 17 + c + 2]; o.w = tl[d * 17 + c + 3];
    *(ushort4*)(xwT + (size_t)d * NN + rb * 16 + c) = o;
}

// ypart[ksl] = adj_bf16 @ xwT^T, 32-row tiles, grid (128, 8).
__global__ __launch_bounds__(256) void gemmA(const float* __restrict__ adj,
                                             const unsigned short* __restrict__ xwT,
                                             float* __restrict__ ypart,
                                             float* __restrict__ dflat) {
    __shared__ __align__(16) unsigned short a_sh[32 * 72];
    __shared__ __align__(16) unsigned short b_sh[64 * 72];
    const int t  = threadIdx.x;
    const int rb = blockIdx.x;                 // 0..127
    const int k0 = blockIdx.y * 512;           // 8 k-slices
    const int w = t >> 6, lane = t & 63;
    const int m = lane & 15, q = lane >> 4;
    const int ih = w & 1, jh = w >> 1;         // row-half, col-half
    const int srow = t >> 3, sq = t & 7;       // A staging: 32 rows x 8 thr
    const int bn = t >> 2, bc = t & 3;         // B staging: 64 rows x 4 thr
    ffrag acc[2];
    acc[0] = (ffrag){0.f, 0.f, 0.f, 0.f};
    acc[1] = (ffrag){0.f, 0.f, 0.f, 0.f};
    float dacc = 0.f;
    const float* abase = adj + (size_t)(rb * 32 + srow) * NN + k0;
    const unsigned short* bbase = xwT + (size_t)bn * NN + k0;
    for (int kt = 0; kt < 512; kt += 64) {
#pragma unroll
        for (int k = 0; k < 2; ++k) {
            const int p = sq + 8 * k;          // float4 slot 0..15
            const float4 v = *(const float4*)(abase + kt + 4 * p);
            dacc += v.x + v.y + v.z + v.w;
            *(uint2*)(a_sh + srow * 72 + 4 * p) = make_uint2(pk2(v.x, v.y), pk2(v.z, v.w));
        }
#pragma unroll
        for (int k = 0; k < 2; ++k) {
            const int c2 = bc + 4 * k;         // bfrag slot 0..7
            *(bfrag*)(b_sh + bn * 72 + c2 * 8) = *(const bfrag*)(bbase + kt + c2 * 8);
        }
        __syncthreads();
#pragma unroll
        for (int ks = 0; ks < 2; ++ks) {
            const bfrag af = *(const bfrag*)(a_sh + (ih * 16 + m) * 72 + ks * 32 + q * 8);
#pragma unroll
            for (int jj = 0; jj < 2; ++jj) {
                const bfrag bf = *(const bfrag*)(b_sh + ((jh * 2 + jj) * 16 + m) * 72 + ks * 32 + q * 8);
                acc[jj] = __builtin_amdgcn_mfma_f32_16x16x32_bf16(af, bf, acc[jj], 0, 0, 0);
            }
        }
        __syncthreads();
    }
    float* op = ypart + (size_t)blockIdx.y * NN * DIM;
#pragma unroll
    for (int jj = 0; jj < 2; ++jj)
#pragma unroll
        for (int r = 0; r < 4; ++r)
            op[(size_t)(rb * 32 + ih * 16 + q * 4 + r) * DIM + jh * 32 + jj * 16 + m] = acc[jj][r];
    dacc += __shfl_down(dacc, 1, 64);
    dacc += __shfl_down(dacc, 2, 64);
    dacc += __shfl_down(dacc, 4, 64);
    if (sq == 0) atomicAdd(&dflat[rb * 32 + srow], dacc);
}

// y = sum(8 y_part) + xw + conv_b ; per-channel sum/sumsq
__global__ __launch_bounds__(256) void bnstat(const float* __restrict__ ypart,
                                              const float* __restrict__ xw,
                                              const float* __restrict__ conv_b,
                                              float* __restrict__ Y0,
                                              float* __restrict__ chsum,
                                              float* __restrict__ chsq) {
    __shared__ float ssum[64], ssq[64];
    const int t = threadIdx.x;
    if (t < 64) { ssum[t] = 0.f; ssq[t] = 0.f; }
    __syncthreads();
    const int tid = blockIdx.x * 256 + t;
    const size_t e = (size_t)tid * 4;
    const int c0 = (int)(e & 63);
    float4 v = *(const float4*)(xw + e);
#pragma unroll
    for (int s = 0; s < 8; ++s) {
        const float4 u = *(const float4*)(ypart + (size_t)s * NN * DIM + e);
        v.x += u.x; v.y += u.y; v.z += u.z; v.w += u.w;
    }
    const float4 b = *(const float4*)(conv_b + c0);
    v.x += b.x; v.y += b.y; v.z += b.z; v.w += b.w;
    *(float4*)(Y0 + e) = v;
    atomicAdd(&ssum[c0 + 0], v.x); atomicAdd(&ssum[c0 + 1], v.y);
    atomicAdd(&ssum[c0 + 2], v.z); atomicAdd(&ssum[c0 + 3], v.w);
    atomicAdd(&ssq[c0 + 0], v.x * v.x); atomicAdd(&ssq[c0 + 1], v.y * v.y);
    atomicAdd(&ssq[c0 + 2], v.z * v.z); atomicAdd(&ssq[c0 + 3], v.w * v.w);
    __syncthreads();
    if (t < 64) { atomicAdd(&chsum[t], ssum[t]); atomicAdd(&chsq[t], ssq[t]); }
}

// per-row: BN affine, L2 norm, softmax -> Sb16 + ST (fused transpose) + YnT; den partials
__global__ __launch_bounds__(256) void rowsk(const float* __restrict__ Y0,
                                             const float* __restrict__ bn_g,
                                             const float* __restrict__ bn_b,
                                             const float* __restrict__ chsum,
                                             const float* __restrict__ chsq,
                                             const float* __restrict__ pool_w,
                                             const float* __restrict__ pool_b,
                                             const float* __restrict__ dflat,
                                             unsigned short* __restrict__ YnT,
                                             unsigned short* __restrict__ Sb16,
                                             unsigned short* __restrict__ ST,
                                             float* __restrict__ denp) {
    __shared__ float scale_sh[64], shift_sh[64];
    __shared__ float yn_sh[4][64];
    __shared__ float4 pw4[16 * 104];   // pw4[dq*104+k] = pool_w[4dq..4dq+3][k]
    __shared__ unsigned short sb_sh[4][128];
    __shared__ float denw[4];
    const int t = threadIdx.x;
    if (t < 64) {
        const float mn  = chsum[t] * (1.f / 4096.f);
        const float var = chsq[t] * (1.f / 4096.f) - mn * mn;
        const float sc  = bn_g[t] * rsqrtf(var + 1e-5f);
        scale_sh[t] = sc;
        shift_sh[t] = bn_b[t] - mn * sc;
    }
    for (int idx = t; idx < 16 * KC; idx += 256) {
        const int dq = idx / KC, k = idx - dq * KC;
        pw4[dq * 104 + k] = make_float4(pool_w[(4 * dq + 0) * KC + k],
                                        pool_w[(4 * dq + 1) * KC + k],
                                        pool_w[(4 * dq + 2) * KC + k],
                                        pool_w[(4 * dq + 3) * KC + k]);
    }
    __syncthreads();
    const int w = t >> 6, lane = t & 63;
    const int row = blockIdx.x * 4 + w;
    float v = Y0[(size_t)row * 64 + lane] * scale_sh[lane] + shift_sh[lane];
    const float nrm = fmaxf(sqrtf(wsum(v * v)), 1e-12f);
    const float yn = v / nrm;
    yn_sh[w][lane] = yn;
    const bool v2 = (lane + 64) < KC;
    const int j2 = v2 ? (lane + 64) : 0;     // clamped (finite garbage, masked later)
    float L1 = pool_b[lane];
    float L2 = pool_b[j2];
    __syncthreads();
#pragma unroll
    for (int dq = 0; dq < 16; ++dq) {
        const float4 yv = *(const float4*)&yn_sh[w][4 * dq];
        const float4 w1 = pw4[dq * 104 + lane];
        L1 += yv.x * w1.x + yv.y * w1.y + yv.z * w1.z + yv.w * w1.w;
        const float4 w2 = pw4[dq * 104 + j2];
        L2 += yv.x * w2.x + yv.y * w2.y + yv.z * w2.z + yv.w * w2.w;
    }
    const float mx = wmax(fmaxf(L1, v2 ? L2 : -1e30f));
    const float e1 = expf(L1 - mx);
    const float e2 = v2 ? expf(L2 - mx) : 0.f;
    const float inv = 1.f / wsum(e1 + e2);
    const float s1 = e1 * inv, s2 = e2 * inv;
    const unsigned short b1 = f2bf(s1), b2 = f2bf(s2);
    Sb16[(size_t)row * 128 + lane] = b1;
    Sb16[(size_t)row * 128 + 64 + lane] = b2;   // zero for cols >= 100
    sb_sh[w][lane] = b1;
    sb_sh[w][64 + lane] = b2;
    const float c = wsum(s1 * s1 + s2 * s2);
    if (lane == 0) denw[w] = dflat[row] * c;
    __syncthreads();
    if (t < 64) {
        // YnT: 4 consecutive rows of column d as one 8B store
        ushort4 o;
        o.x = f2bf(yn_sh[0][t]); o.y = f2bf(yn_sh[1][t]);
        o.z = f2bf(yn_sh[2][t]); o.w = f2bf(yn_sh[3][t]);
        *(ushort4*)(YnT + (size_t)t * NN + blockIdx.x * 4) = o;
    } else if (t < 192) {
        // ST: 4 consecutive rows of S column c as one 8B store
        const int c2 = t - 64;
        ushort4 o;
        o.x = sb_sh[0][c2]; o.y = sb_sh[1][c2];
        o.z = sb_sh[2][c2]; o.w = sb_sh[3][c2];
        *(ushort4*)(ST + (size_t)c2 * NN + blockIdx.x * 4) = o;
    } else if (t == 192) {
        denp[blockIdx.x] = denw[0] + denw[1] + denw[2] + denw[3];
    }
}

// ============================================================================
// xform: fused {gram, gramred, transformer x3, final, spmmT} in one launch.
// grid 256 x 512 threads. Blocks 0..100: transformer (block b owns token b).
// Blocks 101..255: workers (first 64 do gram tiles, then all stripe spmm).
// Transformer: T14 staggered 1-phase-ahead weight prefetch (round 5).
// Workers: register double-buffered k-loop (round 6) -- next k-step's
// global loads stay in flight across the lgkm-only bar() while MFMA runs.
// ============================================================================
__global__ __launch_bounds__(512, 1) void xform(
        const float* __restrict__ adj,
        const unsigned short* __restrict__ ST,
        const unsigned short* __restrict__ Sb16,
        const unsigned short* __restrict__ YnT,
        float* __restrict__ gpart,
        const float* __restrict__ cls,
        float* __restrict__ ssb,
        float* __restrict__ qkvb,
        const float* __restrict__ g1, const float* __restrict__ b1,
        const float* __restrict__ qw, const float* __restrict__ qb,
        const float* __restrict__ pw, const float* __restrict__ pb,
        const float* __restrict__ g2, const float* __restrict__ b2,
        const float* __restrict__ w1, const float* __restrict__ bb1,
        const float* __restrict__ w2, const float* __restrict__ bb2,
        const float* __restrict__ ng, const float* __restrict__ nb,
        const float* __restrict__ hw, const float* __restrict__ hb,
        const float* __restrict__ denp, float* __restrict__ nump,
        unsigned* __restrict__ ctr,
        float* __restrict__ out) {
    __shared__ __align__(16) float big[13332];   // K|V stage / weight chunks / MFMA stage
    __shared__ float scsh[8 * 104];              // scores / probs
    __shared__ __align__(16) float partf[1056];  // cross-group partials / reductions
    __shared__ float q_l[64], osh[64], h2sh[64], h1sh[64], toksh[64], gsh[256];
    __shared__ float redw8[8];
    float (*part)[132] = (float(*)[132])partf;
    const int t = threadIdx.x, b = blockIdx.x;

    if (b < 101) {
        // ================= transformer path =================
        // prefetch layer-0 qkv_w at kernel entry -- hides under the gram wait
        float4 rqkv[6];
        {
            const float4* s4 = (const float4*)qw;
#pragma unroll
            for (int p = 0; p < 6; ++p) rqkv[p] = s4[t + 512 * p];
        }
        // ---- phase G: own gram row -> token (LDS) + ss row ----
        if (b == 0) {
            if (t < 64) toksh[t] = cls[t];
        } else {
            if (t == 0) wait_ge<2>(&ctr[3], 64u);
            bar();
            const int row = b - 1;
            if (t < 384) {
                const int col = t % 192, sg = t / 192;
                float v = 0.f;
                const float* gp = gpart + (size_t)row * 192 + col + (size_t)sg * 32 * 24576;
                for (int s = 0; s < 32; ++s) v += gp[(size_t)s * 24576];
                partf[sg * 192 + col] = v;
            }
            bar();
            if (t < 192) {
                const float v = partf[t] + partf[192 + t];
                if (t < 64) toksh[t] = v;
                else if (t < 164) ssb[row * 100 + (t - 64)] = v;   // published by gbar(l=0)
            }
        }
        bar();
        // ---- LN1 for layer 0 ----
        if (t < 64) {
            const float x = toksh[t];
            const float m = wsum(x) * (1.f / 64.f);
            const float var = wsum(x * x) * (1.f / 64.f) - m * m;
            h1sh[t] = (x - m) * rsqrtf(var + 1e-6f) * g1[t] + b1[t];
        }
        bar();
        for (int l = 0; l < LL; ++l) {
            float* qk = qkvb + (size_t)(l & 1) * (101 * 192);   // ping-pong
            // ---- A: qkv_w regs -> LDS, QKV compute ----
#pragma unroll
            for (int p = 0; p < 6; ++p) ((float4*)big)[t + 512 * p] = rqkv[p];
            bar();
            if (t < 384) {
                const int o = t % 192, grp = t / 192;
                float a = 0.f;
#pragma unroll 8
                for (int e = grp * 32; e < grp * 32 + 32; ++e)
                    a += h1sh[e] * big[e * 192 + o];
                partf[grp * 192 + o] = a;
            }
            bar();
            if (t < 192)
                qk[b * 192 + t] = qb[l * 192 + t] + partf[t] + partf[192 + t];
            // ---- 101-block barrier: all tokens' QKV visible ----
            gbar(&ctr[l], 101u);
            // ---- KV: issue loads, store to LDS ----
            float4 rkv[7], rq;
#pragma unroll
            for (int p = 0; p < 7; ++p) {
                const int idx = t + 512 * p;
                if (idx < 3232)
                    rkv[p] = *(const float4*)(qk + (idx >> 5) * 192 + 64 + (idx & 31) * 4);
            }
            if (t < 16) rq = *(const float4*)(qk + b * 192 + t * 4);
            float t_old = 0.f;
            if (t < 64) t_old = toksh[t];
#pragma unroll
            for (int p = 0; p < 7; ++p) {
                const int idx = t + 512 * p;
                if (idx < 3232) {
                    const int k = idx >> 5, c = idx & 31;
                    *(float4*)&big[k * 132 + c * 4] = rkv[p];
                }
            }
            if (t < 16) *(float4*)&q_l[t * 4] = rq;
            // issue pw prefetch (2 float4) -- consumed at proj
            float4 rpw[2];
#pragma unroll
            for (int p = 0; p < 2; ++p)
                rpw[p] = ((const float4*)(pw + (size_t)l * 4096))[t + 512 * p];
            bar();
            // ---- scores ----
            const float scale = 0.35355339059327373f;
#pragma unroll
            for (int p = 0; p < 2; ++p) {
                const int idx = t + 512 * p;
                if (idx < 808) {
                    const int h = idx / 101, k = idx - h * 101;
                    float s = 0.f;
#pragma unroll
                    for (int d = 0; d < 8; ++d)
                        s += q_l[h * 8 + d] * big[k * 132 + h * 8 + d];
                    scsh[h * 104 + k] = s * scale;
                }
            }
            bar();
            // ---- softmax per head ----
            if (t < 256) {
                const int w = t >> 6;
                const int h = w * 2 + ((t >> 5) & 1);   // head 0..7
                const int lft = t & 31;
                float v[4];
#pragma unroll
                for (int g = 0; g < 4; ++g) {
                    const int k = lft + 32 * g;
                    v[g] = (k < 101) ? scsh[h * 104 + k] : -1e30f;
                }
                float mm = fmaxf(fmaxf(v[0], v[1]), fmaxf(v[2], v[3]));
                mm = hmax32(mm);
                float s = 0.f;
#pragma unroll
                for (int g = 0; g < 4; ++g) { v[g] = expf(v[g] - mm); s += v[g]; }
                s = hsum32(s);
                const float inv = 1.f / s;
#pragma unroll
                for (int g = 0; g < 4; ++g) {
                    const int k = lft + 32 * g;
                    if (k < 101) scsh[h * 104 + k] = v[g] * inv;
                }
            }
            bar();
            // ---- O = P @ V : 8-way k-split ----
            {
                const int o = t & 63, grp = t >> 6;
                float po = 0.f;
                for (int k = grp; k < 101; k += 8)
                    po += scsh[(o >> 3) * 104 + k] * big[k * 132 + 64 + o];
                part[grp][o] = po;
            }
            bar();
            if (t < 64)
                osh[t] = part[0][t] + part[1][t] + part[2][t] + part[3][t]
                       + part[4][t] + part[5][t] + part[6][t] + part[7][t];
            // issue w1-ch0 prefetch (4 float4) -- consumed at fc1-ch0
            float4 rw1a[4];
#pragma unroll
            for (int p = 0; p < 4; ++p) {
                const int idx = t + 512 * p;
                rw1a[p] = *(const float4*)(w1 + (size_t)l * 16384 + (idx >> 5) * 256 + (idx & 31) * 4);
            }
            bar();
            // ---- C: proj ----
#pragma unroll
            for (int p = 0; p < 2; ++p) ((float4*)big)[t + 512 * p] = rpw[p];
            bar();
            {
                const int o = t & 63, grp = t >> 6;
                float pp = 0.f;
#pragma unroll
                for (int e = grp * 8; e < grp * 8 + 8; ++e)
                    pp += osh[e] * big[e * 64 + o];
                part[grp][o] = pp;
            }
            bar();
            float t1 = 0.f;
            if (t < 64) {
                float pr = pb[l * 64 + t];
#pragma unroll
                for (int g = 0; g < 8; ++g) pr += part[g][t];
                t1 = t_old + pr;
                const float m = wsum(t1) * (1.f / 64.f);
                const float var = wsum(t1 * t1) * (1.f / 64.f) - m * m;
                h2sh[t] = (t1 - m) * rsqrtf(var + 1e-6f) * g2[l * 64 + t] + b2[l * 64 + t];
            }
            // issue w1-ch1 prefetch (4 float4) -- consumed at fc1-ch1
            float4 rw1b[4];
#pragma unroll
            for (int p = 0; p < 4; ++p) {
                const int idx = t + 512 * p;
                rw1b[p] = *(const float4*)(w1 + (size_t)l * 16384 + (idx >> 5) * 256 + 128 + (idx & 31) * 4);
            }
            bar();
            // ---- D: fc1-ch0 + GELU ----
#pragma unroll
            for (int p = 0; p < 4; ++p) {
                const int idx = t + 512 * p;
                *(float4*)&big[(idx >> 5) * 128 + (idx & 31) * 4] = rw1a[p];
            }
            bar();
            {
                const int o = t & 127, grp = t >> 7;
                float pa = 0.f;
#pragma unroll
                for (int e = grp * 16; e < grp * 16 + 16; ++e)
                    pa += h2sh[e] * big[e * 128 + o];
                part[grp][o] = pa;
            }
            bar();
            if (t < 128) {
                float a = bb1[l * 256 + t]
                        + part[0][t] + part[1][t] + part[2][t] + part[3][t];
                gsh[t] = 0.5f * a * (1.f + erff(a * 0.70710678118654752f));
            }
            // issue w2-ch0 prefetch (4 float4) -- consumed at fc2-ch0
            float4 rw2a[4];
#pragma unroll
            for (int p = 0; p < 4; ++p)
                rw2a[p] = ((const float4*)(w2 + (size_t)l * 16384))[t + 512 * p];
            bar();
            // ---- fc1-ch1 + GELU ----
#pragma unroll
            for (int p = 0; p < 4; ++p) {
                const int idx = t + 512 * p;
                *(float4*)&big[(idx >> 5) * 128 + (idx & 31) * 4] = rw1b[p];
            }
            bar();
            {
                const int o = t & 127, grp = t >> 7;
                float pa = 0.f;
#pragma unroll
                for (int e = grp * 16; e < grp * 16 + 16; ++e)
                    pa += h2sh[e] * big[e * 128 + o];
                part[grp][o] = pa;
            }
            bar();
            if (t < 128) {
                float a = bb1[l * 256 + 128 + t]
                        + part[0][t] + part[1][t] + part[2][t] + part[3][t];
                gsh[128 + t] = 0.5f * a * (1.f + erff(a * 0.70710678118654752f));
            }
            // issue w2-ch1 prefetch (4 float4) -- consumed at fc2-ch1
            float4 rw2b[4];
#pragma unroll
            for (int p = 0; p < 4; ++p)
                rw2b[p] = ((const float4*)(w2 + (size_t)l * 16384 + 8192))[t + 512 * p];
            bar();
            // ---- E: fc2-ch0 ----
            float a2p = 0.f;
#pragma unroll
            for (int p = 0; p < 4; ++p) ((float4*)big)[t + 512 * p] = rw2a[p];
            bar();
            {
                const int o = t & 63, grp = t >> 6;
#pragma unroll
                for (int er = grp * 16; er < grp * 16 + 16; ++er)
                    a2p += gsh[er] * big[er * 64 + o];
            }
            // issue next-layer qkv_w prefetch (6 float4) -- consumed at next A
            if (l < 2) {
                const float4* s4 = (const float4*)(qw + (size_t)(l + 1) * 12288);
#pragma unroll
                for (int p = 0; p < 6; ++p) rqkv[p] = s4[t + 512 * p];
            }
            bar();
            // ---- fc2-ch1 ----
#pragma unroll
            for (int p = 0; p < 4; ++p) ((float4*)big)[t + 512 * p] = rw2b[p];
            bar();
            {
                const int o = t & 63, grp = t >> 6;
#pragma unroll
                for (int er = grp * 16; er < grp * 16 + 16; ++er)
                    a2p += gsh[128 + er] * big[er * 64 + o];
            }
            {
                const int o = t & 63, grp = t >> 6;
                part[grp][o] = a2p;
            }
            bar();
            if (t < 64) {
                float a2 = bb2[l * 64 + t];
#pragma unroll
                for (int g = 0; g < 8; ++g) a2 += part[g][t];
                const float tn = t1 + a2;
                toksh[t] = tn;
                if (l < 2) {
                    const float m = wsum(tn) * (1.f / 64.f);
                    const float var = wsum(tn * tn) * (1.f / 64.f) - m * m;
                    h1sh[t] = (tn - m) * rsqrtf(var + 1e-6f) * g1[(l + 1) * 64 + t]
                              + b1[(l + 1) * 64 + t];
                }
            }
            bar();
        }
        // ---- final phase (block 0 only): LN + head + losses ----
        if (b == 0) {
            if (t < 64) {
                const float x = toksh[t];
                const float m = wsum(x) * (1.f / 64.f);
                const float var = wsum(x * x) * (1.f / 64.f) - m * m;
                h1sh[t] = (x - m) * rsqrtf(var + 1e-6f) * ng[t] + nb[t];
            }
            if (t == 0) wait_ge<8>(&ctr[4], 155u);
            __syncthreads();
            float* red = partf;
            red[t] = denp[t] + denp[t + 512];
            __syncthreads();
            for (int s = 256; s > 0; s >>= 1) { if (t < s) red[t] += red[t + s]; __syncthreads(); }
            if (t == 0) q_l[0] = red[0];
            __syncthreads();
            red[t] = nump[t] + nump[t + 512];
            __syncthreads();
            for (int s = 256; s > 0; s >>= 1) { if (t < s) red[t] += red[t + s]; __syncthreads(); }
            if (t == 0) q_l[1] = red[0];
            __syncthreads();
            if (t < 2) {
                float a = hb[t];
                for (int d = 0; d < 64; ++d) a += h1sh[d] * hw[d * 2 + t];
                out[t] = a;
            }
            if (t == 2) out[2] = -(q_l[1] / q_l[0]);
            float s1 = 0.f;
            for (int idx = t; idx < KC * KC; idx += 512) { const float v = ssb[idx]; s1 += v * v; }
            __syncthreads();
            red[t] = s1;
            __syncthreads();
            for (int s = 256; s > 0; s >>= 1) { if (t < s) red[t] += red[t + s]; __syncthreads(); }
            if (t == 0) q_l[2] = sqrtf(red[0]);
            __syncthreads();
            const float inv = 1.f / q_l[2];
            float s2 = 0.f;
            for (int idx = t; idx < KC * KC; idx += 512) {
                float v = ssb[idx] * inv;
                if (idx % 101 == 0) v -= 0.1f;   // diag: I/||I||_F = I/10
                s2 += v * v;
            }
            __syncthreads();
            red[t] = s2;
            __syncthreads();
            for (int s = 256; s > 0; s >>= 1) { if (t < s) red[t] += red[t + s]; __syncthreads(); }
            if (t == 0) out[3] = sqrtf(red[0]);
        }
    } else {
        // ================= worker path =================
        const int wb = b - 101;
        const int w = t >> 6, lane = t & 63;
        const int m = lane & 15, q = lane >> 4;
        if (wb < 64) {
            // ---- gram tile wb: C[128][192] partial for k-slice [wb*64, wb*64+64) ----
            unsigned short* a_sh = (unsigned short*)big;               // 128*72
            unsigned short* b_sh = (unsigned short*)big + 128 * 72;    // 192*72
            const int k0 = wb * 64;
            const int n0 = t >> 3, c8 = (t & 7) * 8;
#pragma unroll
            for (int p = 0; p < 2; ++p) {
                const int n = n0 + 64 * p;
                *(bfrag*)(a_sh + n * 72 + c8) = *(const bfrag*)(ST + (size_t)n * NN + k0 + c8);
            }
#pragma unroll
            for (int p = 0; p < 3; ++p) {
                const int n = n0 + 64 * p;
                const unsigned short* src = (n < 64) ? (YnT + (size_t)n * NN + k0 + c8)
                                                     : (ST + (size_t)(n - 64) * NN + k0 + c8);
                *(bfrag*)(b_sh + n * 72 + c8) = *(const bfrag*)src;
            }
            __syncthreads();
            ffrag acc[12];
#pragma unroll
            for (int j = 0; j < 12; ++j) acc[j] = (ffrag){0.f, 0.f, 0.f, 0.f};
#pragma unroll
            for (int ks = 0; ks < 2; ++ks) {
                const bfrag af = *(const bfrag*)(a_sh + (w * 16 + m) * 72 + ks * 32 + q * 8);
#pragma unroll
                for (int j = 0; j < 12; ++j) {
                    const bfrag bf = *(const bfrag*)(b_sh + (j * 16 + m) * 72 + ks * 32 + q * 8);
                    acc[j] = __builtin_amdgcn_mfma_f32_16x16x32_bf16(af, bf, acc[j], 0, 0, 0);
                }
            }
            float* op = gpart + (size_t)wb * 128 * 192;
#pragma unroll
            for (int j = 0; j < 12; ++j)
#pragma unroll
                for (int r = 0; r < 4; ++r)
                    op[(size_t)(w * 16 + q * 4 + r) * 192 + j * 16 + m] = acc[j][r];
            __syncthreads();                       // drains all gpart stores (vmcnt)
            if (t == 0) rel_add(&ctr[3]);          // release publishes them
        }
        // ---- spmm tiles: nump[tile] = sum(S .* (adj @ S)) over 32-row x 512-k tile.
        // Register double-buffer: store staged regs -> issue next k-step loads ->
        // lgkm-only bar() -> MFMA. Next loads stay in flight under MFMA+barriers.
        unsigned short* a_sh = (unsigned short*)big;             // 32*72
        unsigned short* s_sh = (unsigned short*)big + 32 * 72;   // 128*72
        const int rh = w & 1, ch = w >> 1;
        const int srow = t >> 4, sq4 = (t & 15) * 4;
        const int sn = t >> 2, scq = t & 3;
        for (int tile = wb; tile < 1024; tile += 155) {
            const int rb = tile & 127;
            const int k0 = (tile >> 7) * 512;
            ffrag acc[2];
            acc[0] = (ffrag){0.f, 0.f, 0.f, 0.f};
            acc[1] = (ffrag){0.f, 0.f, 0.f, 0.f};
            const float* abase = adj + (size_t)(rb * 32 + srow) * NN + k0;
            const unsigned short* sbase = ST + (size_t)sn * NN + k0;
            // prefetch k-step 0
            float4 av = *(const float4*)(abase + sq4);
            bfrag sv0 = *(const bfrag*)(sbase + scq * 8);
            bfrag sv1 = *(const bfrag*)(sbase + (scq + 4) * 8);
#pragma unroll
            for (int kt = 0; kt < 512; kt += 64) {
                // store current k-step (auto vmcnt wait on av/sv -- already landed)
                *(uint2*)(a_sh + srow * 72 + sq4) = make_uint2(pk2(av.x, av.y), pk2(av.z, av.w));
                *(bfrag*)(s_sh + sn * 72 + scq * 8) = sv0;
                *(bfrag*)(s_sh + sn * 72 + (scq + 4) * 8) = sv1;
                // issue next k-step loads (stay in flight across bar())
                if (kt + 64 < 512) {
                    av  = *(const float4*)(abase + kt + 64 + sq4);
                    sv0 = *(const bfrag*)(sbase + kt + 64 + scq * 8);
                    sv1 = *(const bfrag*)(sbase + kt + 64 + (scq + 4) * 8);
                }
                bar();
#pragma unroll
                for (int ks = 0; ks < 2; ++ks) {
                    const bfrag af = *(const bfrag*)(a_sh + (rh * 16 + m) * 72 + ks * 32 + q * 8);
#pragma unroll
                    for (int j = 0; j < 2; ++j) {
                        const bfrag bf = *(const bfrag*)(s_sh + ((ch * 2 + j) * 16 + m) * 72 + ks * 32 + q * 8);
                        acc[j] = __builtin_amdgcn_mfma_f32_16x16x32_bf16(af, bf, acc[j], 0, 0, 0);
                    }
                }
                bar();
            }
            float local = 0.f;
#pragma unroll
            for (int j = 0; j < 2; ++j)
#pragma unroll
                for (int r = 0; r < 4; ++r) {
                    const int row = rb * 32 + rh * 16 + q * 4 + r;
                    const int col = ch * 32 + j * 16 + m;
                    local += acc[j][r] * bf2f(Sb16[(size_t)row * 128 + col]);
                }
            local = wsum(local);
            if (lane == 0) redw8[w] = local;
            bar();
            if (t == 0) {
                float s = 0.f;
#pragma unroll
                for (int k = 0; k < 8; ++k) s += redw8[k];
                nump[(tile >> 7) * 128 + rb] = s;   // left in flight; drained below
            }
        }
        __syncthreads();                           // drains nump stores
        if (t == 0) rel_add(&ctr[4]);              // release publishes them
    }
}

extern "C" void kernel_launch(void* const* d_in, const int* in_sizes, int n_in,
                              void* d_out, int out_size, void* d_ws, size_t ws_size,
                              hipStream_t stream) {
    (void)in_sizes; (void)n_in; (void)out_size; (void)ws_size;
    const float* x      = (const float*)d_in[0];
    const float* adj    = (const float*)d_in[1];
    const float* conv_w = (const float*)d_in[2];
    const float* conv_b = (const float*)d_in[3];
    const float* bn_g   = (const float*)d_in[4];
    const float* bn_b   = (const float*)d_in[5];
    const float* pool_w = (const float*)d_in[6];
    const float* pool_b = (const float*)d_in[7];
    const float* cls    = (const float*)d_in[8];
    const float* ln1_g  = (const float*)d_in[9];
    const float* ln1_b  = (const float*)d_in[10];
    const float* qkv_w  = (const float*)d_in[11];
    const float* qkv_b  = (const float*)d_in[12];
    const float* proj_w = (const float*)d_in[13];
    const float* proj_b = (const float*)d_in[14];
    const float* ln2_g  = (const float*)d_in[15];
    const float* ln2_b  = (const float*)d_in[16];
    const float* fc1_w  = (const float*)d_in[17];
    const float* fc1_b  = (const float*)d_in[18];
    const float* fc2_w  = (const float*)d_in[19];
    const float* fc2_b  = (const float*)d_in[20];
    const float* norm_g = (const float*)d_in[21];
    const float* norm_b = (const float*)d_in[22];
    const float* head_w = (const float*)d_in[23];
    const float* head_b = (const float*)d_in[24];
    float* ws  = (float*)d_ws;
    float* out = (float*)d_out;
    unsigned short* Sb16  = (unsigned short*)(ws + OFF_SB16);
    unsigned short* STb16 = (unsigned short*)(ws + OFF_STB16);
    unsigned short* YnT16 = (unsigned short*)(ws + OFF_YNT16);
    unsigned short* xwT16 = (unsigned short*)(ws + OFF_XWT16);

    // xw = x @ conv_w (fused zero-init of accumulator region + sync counters)
    xwk<<<256, 256, 0, stream>>>(x, conv_w, ws + OFF_XW, xwT16, ws);
    // y_part = adj @ xw via bf16 MFMA (+ dflat row sums)
    gemmA<<<dim3(128, 8), 256, 0, stream>>>(adj, xwT16, ws + OFF_YPART, ws + OFF_DFLAT);
    bnstat<<<256, 256, 0, stream>>>(ws + OFF_YPART, ws + OFF_XW, conv_b,
                                    ws + OFF_Y0, ws + OFF_CHSUM, ws + OFF_CHSQ);
    rowsk<<<1024, 256, 0, stream>>>(ws + OFF_Y0, bn_g, bn_b, ws + OFF_CHSUM, ws + OFF_CHSQ,
                                    pool_w, pool_b, ws + OFF_DFLAT,
                                    YnT16, Sb16, STb16, ws + OFF_DENP);
    // fused gram + gramred + transformer + final + overlapped spmm
    xform<<<256, 512, 0, stream>>>(adj, STb16, Sb16, YnT16, ws + OFF_GPART, cls,
                                   ws + OFF_SS, ws + OFF_QKV,
                                   ln1_g, ln1_b, qkv_w, qkv_b, proj_w, proj_b,
                                   ln2_g, ln2_b, fc1_w, fc1_b, fc2_w, fc2_b,
                                   norm_g, norm_b, head_w, head_b,
                                   ws + OFF_DENP, ws + OFF_NUMP,
                                   (unsigned*)(ws + OFF_CTR), out);
}

// Round 7
// 258.504 us; speedup vs baseline: 1.1232x; 1.0874x over previous
//
#include <hip/hip_runtime.h>
#include <hip/hip_bf16.h>
#include <math.h>

#define NN   4096
#define FEAT 512
#define DIM  64
#define KC   100
#define LL   3

// ---- workspace layout (float offsets). Total ~20MB.
#define OFF_DFLAT   0                          // [4096] adj row sums (atomic)
#define OFF_CHSUM   4096                       // [64]
#define OFF_CHSQ    4160                       // [64]
#define OFF_CTR     4224                       // [16] barrier/done counters (u32)
#define ZERO_FLOATS 4240                       // zeroed by xwk blocks 0..16
#define OFF_XW      4240                       // [4096*64] fp32
#define OFF_YPART   (OFF_XW + NN*DIM)          // 8 slices fp32
#define OFF_GPART   (OFF_YPART + 8*NN*DIM)     // [64*128*192]
#define OFF_Y0      (OFF_GPART + 64*128*192)   // [4096*64]
#define OFF_QKV     (OFF_Y0 + NN*DIM)          // [2*101*192] ping-pong
#define OFF_SS      (OFF_QKV + 2*101*192)      // [100*100]
#define OFF_DENP    (OFF_SS + KC*KC)           // [1024]
#define OFF_NUMP    (OFF_DENP + 1024)          // [1024]
#define OFF_SB16    (OFF_NUMP + 1024)          // [4096*128] bf16
#define OFF_STB16   (OFF_SB16 + NN*128/2)      // [128*4096] bf16
#define OFF_YNT16   (OFF_STB16 + NN*128/2)     // [64*4096] bf16
#define OFF_XWT16   (OFF_YNT16 + NN*DIM/2)     // [64*4096] bf16

typedef __attribute__((ext_vector_type(8))) short bfrag;   // 8 bf16 (4 VGPRs)
typedef __attribute__((ext_vector_type(4))) float ffrag;   // 4 fp32 acc

__device__ __forceinline__ unsigned short f2bf(float f) {
    union { float f; unsigned u; } v; v.f = f;
    return (unsigned short)((v.u + 0x7FFFu + ((v.u >> 16) & 1u)) >> 16);
}
__device__ __forceinline__ float bf2f(unsigned short u) {
    union { unsigned u; float f; } v; v.u = (unsigned)u << 16; return v.f;
}
__device__ __forceinline__ unsigned int pk2(float a, float b) {
    __hip_bfloat162 h = __float22bfloat162_rn(make_float2(a, b));
    return *(unsigned int*)&h;
}

__device__ __forceinline__ float wsum(float v) {
#pragma unroll
    for (int o = 32; o > 0; o >>= 1) v += __shfl_xor(v, o, 64);
    return v;
}
__device__ __forceinline__ float wmax(float v) {
#pragma unroll
    for (int o = 32; o > 0; o >>= 1) v = fmaxf(v, __shfl_xor(v, o, 64));
    return v;
}
__device__ __forceinline__ float hsum32(float v) {
#pragma unroll
    for (int o = 16; o > 0; o >>= 1) v += __shfl_xor(v, o, 64);
    return v;
}
__device__ __forceinline__ float hmax32(float v) {
#pragma unroll
    for (int o = 16; o > 0; o >>= 1) v = fmaxf(v, __shfl_xor(v, o, 64));
    return v;
}

// ---- device-scope sync primitives (inter-block, co-resident grid) ----
// RELAXED polling (round-1 fix): ACQUIRE per poll emits buffer_inv per
// iteration -> L2 disabled device-wide. Poll relaxed, single acquire fence.
// ROUND-6 FIX (kept): buffer_inv is vmcnt-tracked; drain it before s_barrier
// or other waves read stale L2 lines from the previous graph replay.
__device__ __forceinline__ unsigned rlx_load(const unsigned* p) {
    return __hip_atomic_load(p, __ATOMIC_RELAXED, __HIP_MEMORY_SCOPE_AGENT);
}
__device__ __forceinline__ void rel_add(unsigned* p) {
    __hip_atomic_fetch_add(p, 1u, __ATOMIC_RELEASE, __HIP_MEMORY_SCOPE_AGENT);
}
template <int SLP>
__device__ __forceinline__ void wait_ge(const unsigned* c, unsigned tgt) {
    while (rlx_load(c) < tgt) __builtin_amdgcn_s_sleep(SLP);
    __builtin_amdgcn_fence(__ATOMIC_ACQUIRE, "agent");   // buffer_inv
    asm volatile("s_waitcnt vmcnt(0)" ::: "memory");     // DRAIN the inv
}
// Raw LDS-handoff barrier: waits only lgkmcnt (LDS ops), NOT vmcnt -- keeps
// in-flight global loads alive across the barrier.
__device__ __forceinline__ void bar() {
    asm volatile("s_waitcnt lgkmcnt(0)" ::: "memory");
    __builtin_amdgcn_s_barrier();
}
__device__ __forceinline__ void gbar(unsigned* c, unsigned tgt) {
    __syncthreads();             // FULL drain: publishes this block's global stores
    if (threadIdx.x == 0) {
        rel_add(c);
        wait_ge<4>(c, tgt);      // returns with inv completed
    }
    bar();
}

// xw = x @ conv_w (fp32, K=512 full) -> xw fp32 + xwT bf16. grid 256 x 16 rows.
// Also zero-inits ws[0..ZERO_FLOATS) from blocks 0..16 (incl. barrier counters).
__global__ __launch_bounds__(256) void xwk(const float* __restrict__ x,
                                           const float* __restrict__ B,
                                           float* __restrict__ xw,
                                           unsigned short* __restrict__ xwT,
                                           float* __restrict__ zws) {
    __shared__ float a_sh[16 * 68];
    __shared__ float b_sh[64 * 68];
    __shared__ unsigned short tl[64 * 17];
    const int t = threadIdx.x, rb = blockIdx.x;
    if (rb < 17) {
        const int zi = rb * 256 + t;
        if (zi < ZERO_FLOATS) zws[zi] = 0.f;
    }
    const int r = t >> 4, cg = (t & 15) * 4;
    float4 acc = make_float4(0.f, 0.f, 0.f, 0.f);
    for (int kt = 0; kt < FEAT; kt += 64) {
        *(float4*)&a_sh[(t >> 4) * 68 + (t & 15) * 4] =
            *(const float4*)(x + (size_t)(rb * 16 + (t >> 4)) * FEAT + kt + (t & 15) * 4);
#pragma unroll
        for (int p = 0; p < 4; ++p) {
            const int idx = t + 256 * p;
            const int kr = idx >> 4, c4 = (idx & 15) * 4;
            *(float4*)&b_sh[kr * 68 + c4] = *(const float4*)(B + (size_t)(kt + kr) * DIM + c4);
        }
        __syncthreads();
#pragma unroll 8
        for (int k = 0; k < 64; ++k) {
            const float av = a_sh[r * 68 + k];
            const float4 bv = *(float4*)&b_sh[k * 68 + cg];
            acc.x += av * bv.x; acc.y += av * bv.y;
            acc.z += av * bv.z; acc.w += av * bv.w;
        }
        __syncthreads();
    }
    *(float4*)&xw[(size_t)(rb * 16 + r) * DIM + cg] = acc;
    tl[(cg + 0) * 17 + r] = f2bf(acc.x);
    tl[(cg + 1) * 17 + r] = f2bf(acc.y);
    tl[(cg + 2) * 17 + r] = f2bf(acc.z);
    tl[(cg + 3) * 17 + r] = f2bf(acc.w);
    __syncthreads();
    const int d = t >> 2, c = (t & 3) * 4;
    ushort4 o;
    o.x = tl[d * 17 + c + 0]; o.y = tl[d * 17 + c + 1];
    o.z = tl[d * 17 + c + 2]; o.w = tl[d * 17 + c + 3];
    *(ushort4*)(xwT + (size_t)d * NN + rb * 16 + c) = o;
}

// ypart[ksl] = adj_bf16 @ xwT^T, 32-row tiles, grid (128, 8).
__global__ __launch_bounds__(256) void gemmA(const float* __restrict__ adj,
                                             const unsigned short* __restrict__ xwT,
                                             float* __restrict__ ypart,
                                             float* __restrict__ dflat) {
    __shared__ __align__(16) unsigned short a_sh[32 * 72];
    __shared__ __align__(16) unsigned short b_sh[64 * 72];
    const int t  = threadIdx.x;
    const int rb = blockIdx.x;                 // 0..127
    const int k0 = blockIdx.y * 512;           // 8 k-slices
    const int w = t >> 6, lane = t & 63;
    const int m = lane & 15, q = lane >> 4;
    const int ih = w & 1, jh = w >> 1;         // row-half, col-half
    const int srow = t >> 3, sq = t & 7;       // A staging: 32 rows x 8 thr
    const int bn = t >> 2, bc = t & 3;         // B staging: 64 rows x 4 thr
    ffrag acc[2];
    acc[0] = (ffrag){0.f, 0.f, 0.f, 0.f};
    acc[1] = (ffrag){0.f, 0.f, 0.f, 0.f};
    float dacc = 0.f;
    const float* abase = adj + (size_t)(rb * 32 + srow) * NN + k0;
    const unsigned short* bbase = xwT + (size_t)bn * NN + k0;
    for (int kt = 0; kt < 512; kt += 64) {
#pragma unroll
        for (int k = 0; k < 2; ++k) {
            const int p = sq + 8 * k;          // float4 slot 0..15
            const float4 v = *(const float4*)(abase + kt + 4 * p);
            dacc += v.x + v.y + v.z + v.w;
            *(uint2*)(a_sh + srow * 72 + 4 * p) = make_uint2(pk2(v.x, v.y), pk2(v.z, v.w));
        }
#pragma unroll
        for (int k = 0; k < 2; ++k) {
            const int c2 = bc + 4 * k;         // bfrag slot 0..7
            *(bfrag*)(b_sh + bn * 72 + c2 * 8) = *(const bfrag*)(bbase + kt + c2 * 8);
        }
        __syncthreads();
#pragma unroll
        for (int ks = 0; ks < 2; ++ks) {
            const bfrag af = *(const bfrag*)(a_sh + (ih * 16 + m) * 72 + ks * 32 + q * 8);
#pragma unroll
            for (int jj = 0; jj < 2; ++jj) {
                const bfrag bf = *(const bfrag*)(b_sh + ((jh * 2 + jj) * 16 + m) * 72 + ks * 32 + q * 8);
                acc[jj] = __builtin_amdgcn_mfma_f32_16x16x32_bf16(af, bf, acc[jj], 0, 0, 0);
            }
        }
        __syncthreads();
    }
    float* op = ypart + (size_t)blockIdx.y * NN * DIM;
#pragma unroll
    for (int jj = 0; jj < 2; ++jj)
#pragma unroll
        for (int r = 0; r < 4; ++r)
            op[(size_t)(rb * 32 + ih * 16 + q * 4 + r) * DIM + jh * 32 + jj * 16 + m] = acc[jj][r];
    dacc += __shfl_down(dacc, 1, 64);
    dacc += __shfl_down(dacc, 2, 64);
    dacc += __shfl_down(dacc, 4, 64);
    if (sq == 0) atomicAdd(&dflat[rb * 32 + srow], dacc);
}

// y = sum(8 y_part) + xw + conv_b ; per-channel sum/sumsq
__global__ __launch_bounds__(256) void bnstat(const float* __restrict__ ypart,
                                              const float* __restrict__ xw,
                                              const float* __restrict__ conv_b,
                                              float* __restrict__ Y0,
                                              float* __restrict__ chsum,
                                              float* __restrict__ chsq) {
    __shared__ float ssum[64], ssq[64];
    const int t = threadIdx.x;
    if (t < 64) { ssum[t] = 0.f; ssq[t] = 0.f; }
    __syncthreads();
    const int tid = blockIdx.x * 256 + t;
    const size_t e = (size_t)tid * 4;
    const int c0 = (int)(e & 63);
    float4 v = *(const float4*)(xw + e);
#pragma unroll
    for (int s = 0; s < 8; ++s) {
        const float4 u = *(const float4*)(ypart + (size_t)s * NN * DIM + e);
        v.x += u.x; v.y += u.y; v.z += u.z; v.w += u.w;
    }
    const float4 b = *(const float4*)(conv_b + c0);
    v.x += b.x; v.y += b.y; v.z += b.z; v.w += b.w;
    *(float4*)(Y0 + e) = v;
    atomicAdd(&ssum[c0 + 0], v.x); atomicAdd(&ssum[c0 + 1], v.y);
    atomicAdd(&ssum[c0 + 2], v.z); atomicAdd(&ssum[c0 + 3], v.w);
    atomicAdd(&ssq[c0 + 0], v.x * v.x); atomicAdd(&ssq[c0 + 1], v.y * v.y);
    atomicAdd(&ssq[c0 + 2], v.z * v.z); atomicAdd(&ssq[c0 + 3], v.w * v.w);
    __syncthreads();
    if (t < 64) { atomicAdd(&chsum[t], ssum[t]); atomicAdd(&chsq[t], ssq[t]); }
}

// per-row: BN affine, L2 norm, softmax -> Sb16 + ST (fused transpose) + YnT; den partials
__global__ __launch_bounds__(256) void rowsk(const float* __restrict__ Y0,
                                             const float* __restrict__ bn_g,
                                             const float* __restrict__ bn_b,
                                             const float* __restrict__ chsum,
                                             const float* __restrict__ chsq,
                                             const float* __restrict__ pool_w,
                                             const float* __restrict__ pool_b,
                                             const float* __restrict__ dflat,
                                             unsigned short* __restrict__ YnT,
                                             unsigned short* __restrict__ Sb16,
                                             unsigned short* __restrict__ ST,
                                             float* __restrict__ denp) {
    __shared__ float scale_sh[64], shift_sh[64];
    __shared__ float yn_sh[4][64];
    __shared__ float4 pw4[16 * 104];   // pw4[dq*104+k] = pool_w[4dq..4dq+3][k]
    __shared__ unsigned short sb_sh[4][128];
    __shared__ float denw[4];
    const int t = threadIdx.x;
    if (t < 64) {
        const float mn  = chsum[t] * (1.f / 4096.f);
        const float var = chsq[t] * (1.f / 4096.f) - mn * mn;
        const float sc  = bn_g[t] * rsqrtf(var + 1e-5f);
        scale_sh[t] = sc;
        shift_sh[t] = bn_b[t] - mn * sc;
    }
    for (int idx = t; idx < 16 * KC; idx += 256) {
        const int dq = idx / KC, k = idx - dq * KC;
        pw4[dq * 104 + k] = make_float4(pool_w[(4 * dq + 0) * KC + k],
                                        pool_w[(4 * dq + 1) * KC + k],
                                        pool_w[(4 * dq + 2) * KC + k],
                                        pool_w[(4 * dq + 3) * KC + k]);
    }
    __syncthreads();
    const int w = t >> 6, lane = t & 63;
    const int row = blockIdx.x * 4 + w;
    float v = Y0[(size_t)row * 64 + lane] * scale_sh[lane] + shift_sh[lane];
    const float nrm = fmaxf(sqrtf(wsum(v * v)), 1e-12f);
    const float yn = v / nrm;
    yn_sh[w][lane] = yn;
    const bool v2 = (lane + 64) < KC;
    const int j2 = v2 ? (lane + 64) : 0;     // clamped (finite garbage, masked later)
    float L1 = pool_b[lane];
    float L2 = pool_b[j2];
    __syncthreads();
#pragma unroll
    for (int dq = 0; dq < 16; ++dq) {
        const float4 yv = *(const float4*)&yn_sh[w][4 * dq];
        const float4 w1 = pw4[dq * 104 + lane];
        L1 += yv.x * w1.x + yv.y * w1.y + yv.z * w1.z + yv.w * w1.w;
        const float4 w2 = pw4[dq * 104 + j2];
        L2 += yv.x * w2.x + yv.y * w2.y + yv.z * w2.z + yv.w * w2.w;
    }
    const float mx = wmax(fmaxf(L1, v2 ? L2 : -1e30f));
    const float e1 = expf(L1 - mx);
    const float e2 = v2 ? expf(L2 - mx) : 0.f;
    const float inv = 1.f / wsum(e1 + e2);
    const float s1 = e1 * inv, s2 = e2 * inv;
    const unsigned short b1 = f2bf(s1), b2 = f2bf(s2);
    Sb16[(size_t)row * 128 + lane] = b1;
    Sb16[(size_t)row * 128 + 64 + lane] = b2;   // zero for cols >= 100
    sb_sh[w][lane] = b1;
    sb_sh[w][64 + lane] = b2;
    const float c = wsum(s1 * s1 + s2 * s2);
    if (lane == 0) denw[w] = dflat[row] * c;
    __syncthreads();
    if (t < 64) {
        // YnT: 4 consecutive rows of column d as one 8B store
        ushort4 o;
        o.x = f2bf(yn_sh[0][t]); o.y = f2bf(yn_sh[1][t]);
        o.z = f2bf(yn_sh[2][t]); o.w = f2bf(yn_sh[3][t]);
        *(ushort4*)(YnT + (size_t)t * NN + blockIdx.x * 4) = o;
    } else if (t < 192) {
        // ST: 4 consecutive rows of S column c as one 8B store
        const int c2 = t - 64;
        ushort4 o;
        o.x = sb_sh[0][c2]; o.y = sb_sh[1][c2];
        o.z = sb_sh[2][c2]; o.w = sb_sh[3][c2];
        *(ushort4*)(ST + (size_t)c2 * NN + blockIdx.x * 4) = o;
    } else if (t == 192) {
        denp[blockIdx.x] = denw[0] + denw[1] + denw[2] + denw[3];
    }
}

// ============================================================================
// xform: fused {gram, gramred, transformer x3, final, spmmT} in one launch.
// grid 256 x 512 threads. Blocks 0..100: transformer (block b owns token b).
// Blocks 101..255: workers (first 64 do gram tiles, then all stripe spmm).
// ROUND-7: NO weight/KV LDS staging in the transformer. Reuse analysis: each
// weight / K / V element is read by exactly ONE thread of the block -- LDS
// staging was a pure global->reg->LDS->reg round trip (and its reg-prefetch
// variant spilled ~30MB to scratch in r4/r6). Phases now read weights
// directly from global (coalesced per-e rows; L2-warm after first touch).
// Workers: spmm k-loop prefetch deepened to 2 steps (adj is HBM, ~900cy).
// ============================================================================
__global__ __launch_bounds__(512) void xform(
        const float* __restrict__ adj,
        const unsigned short* __restrict__ ST,
        const unsigned short* __restrict__ Sb16,
        const unsigned short* __restrict__ YnT,
        float* __restrict__ gpart,
        const float* __restrict__ cls,
        float* __restrict__ ssb,
        float* __restrict__ qkvb,
        const float* __restrict__ g1, const float* __restrict__ b1,
        const float* __restrict__ qw, const float* __restrict__ qb,
        const float* __restrict__ pw, const float* __restrict__ pb,
        const float* __restrict__ g2, const float* __restrict__ b2,
        const float* __restrict__ w1, const float* __restrict__ bb1,
        const float* __restrict__ w2, const float* __restrict__ bb2,
        const float* __restrict__ ng, const float* __restrict__ nb,
        const float* __restrict__ hw, const float* __restrict__ hb,
        const float* __restrict__ denp, float* __restrict__ nump,
        unsigned* __restrict__ ctr,
        float* __restrict__ out) {
    __shared__ __align__(16) float big[13332];   // worker MFMA staging only
    __shared__ float scsh[8 * 104];              // scores / probs
    __shared__ __align__(16) float partf[1056];  // cross-group partials / reductions
    __shared__ float q_l[64], osh[64], h2sh[64], h1sh[64], toksh[64], gsh[256];
    __shared__ float redw8[8];
    float (*part)[132] = (float(*)[132])partf;
    const int t = threadIdx.x, b = blockIdx.x;

    if (b < 101) {
        // ================= transformer path =================
        // ---- phase G: own gram row -> token (LDS) + ss row ----
        if (b == 0) {
            if (t < 64) toksh[t] = cls[t];
        } else {
            if (t == 0) wait_ge<2>(&ctr[3], 64u);
            bar();
            const int row = b - 1;
            if (t < 384) {
                const int col = t % 192, sg = t / 192;
                float v = 0.f;
                const float* gp = gpart + (size_t)row * 192 + col + (size_t)sg * 32 * 24576;
                for (int s = 0; s < 32; ++s) v += gp[(size_t)s * 24576];
                partf[sg * 192 + col] = v;
            }
            bar();
            if (t < 192) {
                const float v = partf[t] + partf[192 + t];
                if (t < 64) toksh[t] = v;
                else if (t < 164) ssb[row * 100 + (t - 64)] = v;   // published by gbar(l=0)
            }
        }
        bar();
        // ---- LN1 for layer 0 ----
        if (t < 64) {
            const float x = toksh[t];
            const float m = wsum(x) * (1.f / 64.f);
            const float var = wsum(x * x) * (1.f / 64.f) - m * m;
            h1sh[t] = (x - m) * rsqrtf(var + 1e-6f) * g1[t] + b1[t];
        }
        bar();
        for (int l = 0; l < LL; ++l) {
            float* qk = qkvb + (size_t)(l & 1) * (101 * 192);   // ping-pong
            // ---- QKV: direct weight reads ----
            if (t < 384) {
                const int o = t % 192, grp = t / 192;
                const float* wp = qw + (size_t)l * 12288 + grp * 32 * 192 + o;
                float a = 0.f;
#pragma unroll
                for (int e = 0; e < 32; ++e) a += h1sh[grp * 32 + e] * wp[e * 192];
                partf[grp * 192 + o] = a;
            }
            bar();
            if (t < 192)
                qk[b * 192 + t] = qb[l * 192 + t] + partf[t] + partf[192 + t];
            // ---- 101-block barrier: all tokens' QKV visible ----
            gbar(&ctr[l], 101u);
            float t_old = 0.f;
            if (t < 64) t_old = toksh[t];
            // ---- stage own q (only reused datum) ----
            if (t < 16) *(float4*)&q_l[t * 4] = *(const float4*)(qk + b * 192 + t * 4);
            bar();
            // ---- scores: direct K reads ----
            const float scale = 0.35355339059327373f;
#pragma unroll
            for (int p = 0; p < 2; ++p) {
                const int idx = t + 512 * p;
                if (idx < 808) {
                    const int h = idx / 101, k = idx - h * 101;
                    const float* kp = qk + k * 192 + 64 + h * 8;
                    float s = 0.f;
#pragma unroll
                    for (int d = 0; d < 8; ++d)
                        s += q_l[h * 8 + d] * kp[d];
                    scsh[h * 104 + k] = s * scale;
                }
            }
            bar();
            // ---- softmax per head ----
            if (t < 256) {
                const int w = t >> 6;
                const int h = w * 2 + ((t >> 5) & 1);   // head 0..7
                const int lft = t & 31;
                float v[4];
#pragma unroll
                for (int g = 0; g < 4; ++g) {
                    const int k = lft + 32 * g;
                    v[g] = (k < 101) ? scsh[h * 104 + k] : -1e30f;
                }
                float mm = fmaxf(fmaxf(v[0], v[1]), fmaxf(v[2], v[3]));
                mm = hmax32(mm);
                float s = 0.f;
#pragma unroll
                for (int g = 0; g < 4; ++g) { v[g] = expf(v[g] - mm); s += v[g]; }
                s = hsum32(s);
                const float inv = 1.f / s;
#pragma unroll
                for (int g = 0; g < 4; ++g) {
                    const int k = lft + 32 * g;
                    if (k < 101) scsh[h * 104 + k] = v[g] * inv;
                }
            }
            bar();
            // ---- O = P @ V : direct V reads, 8-way k-split ----
            {
                const int o = t & 63, grp = t >> 6;
                float po = 0.f;
                for (int k = grp; k < 101; k += 8)
                    po += scsh[(o >> 3) * 104 + k] * qk[k * 192 + 128 + o];
                part[grp][o] = po;
            }
            bar();
            if (t < 64)
                osh[t] = part[0][t] + part[1][t] + part[2][t] + part[3][t]
                       + part[4][t] + part[5][t] + part[6][t] + part[7][t];
            bar();
            // ---- proj: direct pw reads ----
            {
                const int o = t & 63, grp = t >> 6;
                const float* wp = pw + (size_t)l * 4096 + grp * 8 * 64 + o;
                float pp = 0.f;
#pragma unroll
                for (int e = 0; e < 8; ++e) pp += osh[grp * 8 + e] * wp[e * 64];
                part[grp][o] = pp;
            }
            bar();
            float t1 = 0.f;
            if (t < 64) {
                float pr = pb[l * 64 + t];
#pragma unroll
                for (int g = 0; g < 8; ++g) pr += part[g][t];
                t1 = t_old + pr;
                const float m = wsum(t1) * (1.f / 64.f);
                const float var = wsum(t1 * t1) * (1.f / 64.f) - m * m;
                h2sh[t] = (t1 - m) * rsqrtf(var + 1e-6f) * g2[l * 64 + t] + b2[l * 64 + t];
            }
            bar();
            // ---- fc1: direct w1 reads (2 grps x 32 e, o in [0,256)) ----
            {
                const int o = t & 255, grp = t >> 8;
                const float* wp = w1 + (size_t)l * 16384 + grp * 32 * 256 + o;
                float pa = 0.f;
#pragma unroll
                for (int e = 0; e < 32; ++e) pa += h2sh[grp * 32 + e] * wp[e * 256];
                partf[grp * 256 + o] = pa;
            }
            bar();
            if (t < 256) {
                float a = bb1[l * 256 + t] + partf[t] + partf[256 + t];
                gsh[t] = 0.5f * a * (1.f + erff(a * 0.70710678118654752f));
            }
            bar();
            // ---- fc2: direct w2 reads (8 grps x 32 er, o in [0,64)) ----
            {
                const int o = t & 63, grp = t >> 6;
                const float* wp = w2 + (size_t)l * 16384 + grp * 32 * 64 + o;
                float a2p = 0.f;
#pragma unroll
                for (int er = 0; er < 32; ++er) a2p += gsh[grp * 32 + er] * wp[er * 64];
                part[grp][o] = a2p;
            }
            bar();
            if (t < 64) {
                float a2 = bb2[l * 64 + t];
#pragma unroll
                for (int g = 0; g < 8; ++g) a2 += part[g][t];
                const float tn = t1 + a2;
                toksh[t] = tn;
                if (l < 2) {
                    const float m = wsum(tn) * (1.f / 64.f);
                    const float var = wsum(tn * tn) * (1.f / 64.f) - m * m;
                    h1sh[t] = (tn - m) * rsqrtf(var + 1e-6f) * g1[(l + 1) * 64 + t]
                              + b1[(l + 1) * 64 + t];
                }
            }
            bar();
        }
        // ---- final phase (block 0 only): LN + head + losses ----
        if (b == 0) {
            if (t < 64) {
                const float x = toksh[t];
                const float m = wsum(x) * (1.f / 64.f);
                const float var = wsum(x * x) * (1.f / 64.f) - m * m;
                h1sh[t] = (x - m) * rsqrtf(var + 1e-6f) * ng[t] + nb[t];
            }
            if (t == 0) wait_ge<8>(&ctr[4], 155u);
            __syncthreads();
            float* red = partf;
            red[t] = denp[t] + denp[t + 512];
            __syncthreads();
            for (int s = 256; s > 0; s >>= 1) { if (t < s) red[t] += red[t + s]; __syncthreads(); }
            if (t == 0) q_l[0] = red[0];
            __syncthreads();
            red[t] = nump[t] + nump[t + 512];
            __syncthreads();
            for (int s = 256; s > 0; s >>= 1) { if (t < s) red[t] += red[t + s]; __syncthreads(); }
            if (t == 0) q_l[1] = red[0];
            __syncthreads();
            if (t < 2) {
                float a = hb[t];
                for (int d = 0; d < 64; ++d) a += h1sh[d] * hw[d * 2 + t];
                out[t] = a;
            }
            if (t == 2) out[2] = -(q_l[1] / q_l[0]);
            float s1 = 0.f;
            for (int idx = t; idx < KC * KC; idx += 512) { const float v = ssb[idx]; s1 += v * v; }
            __syncthreads();
            red[t] = s1;
            __syncthreads();
            for (int s = 256; s > 0; s >>= 1) { if (t < s) red[t] += red[t + s]; __syncthreads(); }
            if (t == 0) q_l[2] = sqrtf(red[0]);
            __syncthreads();
            const float inv = 1.f / q_l[2];
            float s2 = 0.f;
            for (int idx = t; idx < KC * KC; idx += 512) {
                float v = ssb[idx] * inv;
                if (idx % 101 == 0) v -= 0.1f;   // diag: I/||I||_F = I/10
                s2 += v * v;
            }
            __syncthreads();
            red[t] = s2;
            __syncthreads();
            for (int s = 256; s > 0; s >>= 1) { if (t < s) red[t] += red[t + s]; __syncthreads(); }
            if (t == 0) out[3] = sqrtf(red[0]);
        }
    } else {
        // ================= worker path =================
        const int wb = b - 101;
        const int w = t >> 6, lane = t & 63;
        const int m = lane & 15, q = lane >> 4;
        if (wb < 64) {
            // ---- gram tile wb: C[128][192] partial for k-slice [wb*64, wb*64+64) ----
            unsigned short* a_sh = (unsigned short*)big;               // 128*72
            unsigned short* b_sh = (unsigned short*)big + 128 * 72;    // 192*72
            const int k0 = wb * 64;
            const int n0 = t >> 3, c8 = (t & 7) * 8;
#pragma unroll
            for (int p = 0; p < 2; ++p) {
                const int n = n0 + 64 * p;
                *(bfrag*)(a_sh + n * 72 + c8) = *(const bfrag*)(ST + (size_t)n * NN + k0 + c8);
            }
#pragma unroll
            for (int p = 0; p < 3; ++p) {
                const int n = n0 + 64 * p;
                const unsigned short* src = (n < 64) ? (YnT + (size_t)n * NN + k0 + c8)
                                                     : (ST + (size_t)(n - 64) * NN + k0 + c8);
                *(bfrag*)(b_sh + n * 72 + c8) = *(const bfrag*)src;
            }
            __syncthreads();
            ffrag acc[12];
#pragma unroll
            for (int j = 0; j < 12; ++j) acc[j] = (ffrag){0.f, 0.f, 0.f, 0.f};
#pragma unroll
            for (int ks = 0; ks < 2; ++ks) {
                const bfrag af = *(const bfrag*)(a_sh + (w * 16 + m) * 72 + ks * 32 + q * 8);
#pragma unroll
                for (int j = 0; j < 12; ++j) {
                    const bfrag bf = *(const bfrag*)(b_sh + (j * 16 + m) * 72 + ks * 32 + q * 8);
                    acc[j] = __builtin_amdgcn_mfma_f32_16x16x32_bf16(af, bf, acc[j], 0, 0, 0);
                }
            }
            float* op = gpart + (size_t)wb * 128 * 192;
#pragma unroll
            for (int j = 0; j < 12; ++j)
#pragma unroll
                for (int r = 0; r < 4; ++r)
                    op[(size_t)(w * 16 + q * 4 + r) * 192 + j * 16 + m] = acc[j][r];
            __syncthreads();                       // drains all gpart stores (vmcnt)
            if (t == 0) rel_add(&ctr[3]);          // release publishes them
        }
        // ---- spmm tiles: nump[tile] = sum(S .* (adj @ S)) over 32-row x 512-k tile.
        // 2-deep register prefetch: loads for k-step N+2 issued while step N
        // computes; stores wait only on their own (2-iteration-old) loads.
        unsigned short* a_sh = (unsigned short*)big;             // 32*72
        unsigned short* s_sh = (unsigned short*)big + 32 * 72;   // 128*72
        const int rh = w & 1, ch = w >> 1;
        const int srow = t >> 4, sq4 = (t & 15) * 4;
        const int sn = t >> 2, scq = t & 3;
        for (int tile = wb; tile < 1024; tile += 155) {
            const int rb = tile & 127;
            const int k0 = (tile >> 7) * 512;
            ffrag acc[2];
            acc[0] = (ffrag){0.f, 0.f, 0.f, 0.f};
            acc[1] = (ffrag){0.f, 0.f, 0.f, 0.f};
            const float* abase = adj + (size_t)(rb * 32 + srow) * NN + k0;
            const unsigned short* sbase = ST + (size_t)sn * NN + k0;
            // prefetch k-steps 0 and 64
            float4 av_a = *(const float4*)(abase + sq4);
            bfrag sa0 = *(const bfrag*)(sbase + scq * 8);
            bfrag sa1 = *(const bfrag*)(sbase + (scq + 4) * 8);
            float4 av_b = *(const float4*)(abase + 64 + sq4);
            bfrag sb0 = *(const bfrag*)(sbase + 64 + scq * 8);
            bfrag sb1 = *(const bfrag*)(sbase + 64 + (scq + 4) * 8);
#pragma unroll
            for (int kt = 0; kt < 512; kt += 128) {
                // step A (kt): store regs -> LDS, refill A-slot from kt+128
                *(uint2*)(a_sh + srow * 72 + sq4) = make_uint2(pk2(av_a.x, av_a.y), pk2(av_a.z, av_a.w));
                *(bfrag*)(s_sh + sn * 72 + scq * 8) = sa0;
                *(bfrag*)(s_sh + sn * 72 + (scq + 4) * 8) = sa1;
                if (kt + 128 < 512) {
                    av_a = *(const float4*)(abase + kt + 128 + sq4);
                    sa0  = *(const bfrag*)(sbase + kt + 128 + scq * 8);
                    sa1  = *(const bfrag*)(sbase + kt + 128 + (scq + 4) * 8);
                }
                bar();
#pragma unroll
                for (int ks = 0; ks < 2; ++ks) {
                    const bfrag af = *(const bfrag*)(a_sh + (rh * 16 + m) * 72 + ks * 32 + q * 8);
#pragma unroll
                    for (int j = 0; j < 2; ++j) {
                        const bfrag bf = *(const bfrag*)(s_sh + ((ch * 2 + j) * 16 + m) * 72 + ks * 32 + q * 8);
                        acc[j] = __builtin_amdgcn_mfma_f32_16x16x32_bf16(af, bf, acc[j], 0, 0, 0);
                    }
                }
                bar();
                // step B (kt+64): store regs -> LDS, refill B-slot from kt+192
                *(uint2*)(a_sh + srow * 72 + sq4) = make_uint2(pk2(av_b.x, av_b.y), pk2(av_b.z, av_b.w));
                *(bfrag*)(s_sh + sn * 72 + scq * 8) = sb0;
                *(bfrag*)(s_sh + sn * 72 + (scq + 4) * 8) = sb1;
                if (kt + 192 < 512) {
                    av_b = *(const float4*)(abase + kt + 192 + sq4);
                    sb0  = *(const bfrag*)(sbase + kt + 192 + scq * 8);
                    sb1  = *(const bfrag*)(sbase + kt + 192 + (scq + 4) * 8);
                }
                bar();
#pragma unroll
                for (int ks = 0; ks < 2; ++ks) {
                    const bfrag af = *(const bfrag*)(a_sh + (rh * 16 + m) * 72 + ks * 32 + q * 8);
#pragma unroll
                    for (int j = 0; j < 2; ++j) {
                        const bfrag bf = *(const bfrag*)(s_sh + ((ch * 2 + j) * 16 + m) * 72 + ks * 32 + q * 8);
                        acc[j] = __builtin_amdgcn_mfma_f32_16x16x32_bf16(af, bf, acc[j], 0, 0, 0);
                    }
                }
                bar();
            }
            float local = 0.f;
#pragma unroll
            for (int j = 0; j < 2; ++j)
#pragma unroll
                for (int r = 0; r < 4; ++r) {
                    const int row = rb * 32 + rh * 16 + q * 4 + r;
                    const int col = ch * 32 + j * 16 + m;
                    local += acc[j][r] * bf2f(Sb16[(size_t)row * 128 + col]);
                }
            local = wsum(local);
            if (lane == 0) redw8[w] = local;
            bar();
            if (t == 0) {
                float s = 0.f;
#pragma unroll
                for (int k = 0; k < 8; ++k) s += redw8[k];
                nump[(tile >> 7) * 128 + rb] = s;   // left in flight; drained below
            }
        }
        __syncthreads();                           // drains nump stores
        if (t == 0) rel_add(&ctr[4]);              // release publishes them
    }
}

extern "C" void kernel_launch(void* const* d_in, const int* in_sizes, int n_in,
                              void* d_out, int out_size, void* d_ws, size_t ws_size,
                              hipStream_t stream) {
    (void)in_sizes; (void)n_in; (void)out_size; (void)ws_size;
    const float* x      = (const float*)d_in[0];
    const float* adj    = (const float*)d_in[1];
    const float* conv_w = (const float*)d_in[2];
    const float* conv_b = (const float*)d_in[3];
    const float* bn_g   = (const float*)d_in[4];
    const float* bn_b   = (const float*)d_in[5];
    const float* pool_w = (const float*)d_in[6];
    const float* pool_b = (const float*)d_in[7];
    const float* cls    = (const float*)d_in[8];
    const float* ln1_g  = (const float*)d_in[9];
    const float* ln1_b  = (const float*)d_in[10];
    const float* qkv_w  = (const float*)d_in[11];
    const float* qkv_b  = (const float*)d_in[12];
    const float* proj_w = (const float*)d_in[13];
    const float* proj_b = (const float*)d_in[14];
    const float* ln2_g  = (const float*)d_in[15];
    const float* ln2_b  = (const float*)d_in[16];
    const float* fc1_w  = (const float*)d_in[17];
    const float* fc1_b  = (const float*)d_in[18];
    const float* fc2_w  = (const float*)d_in[19];
    const float* fc2_b  = (const float*)d_in[20];
    const float* norm_g = (const float*)d_in[21];
    const float* norm_b = (const float*)d_in[22];
    const float* head_w = (const float*)d_in[23];
    const float* head_b = (const float*)d_in[24];
    float* ws  = (float*)d_ws;
    float* out = (float*)d_out;
    unsigned short* Sb16  = (unsigned short*)(ws + OFF_SB16);
    unsigned short* STb16 = (unsigned short*)(ws + OFF_STB16);
    unsigned short* YnT16 = (unsigned short*)(ws + OFF_YNT16);
    unsigned short* xwT16 = (unsigned short*)(ws + OFF_XWT16);

    // xw = x @ conv_w (fused zero-init of accumulator region + sync counters)
    xwk<<<256, 256, 0, stream>>>(x, conv_w, ws + OFF_XW, xwT16, ws);
    // y_part = adj @ xw via bf16 MFMA (+ dflat row sums)
    gemmA<<<dim3(128, 8), 256, 0, stream>>>(adj, xwT16, ws + OFF_YPART, ws + OFF_DFLAT);
    bnstat<<<256, 256, 0, stream>>>(ws + OFF_YPART, ws + OFF_XW, conv_b,
                                    ws + OFF_Y0, ws + OFF_CHSUM, ws + OFF_CHSQ);
    rowsk<<<1024, 256, 0, stream>>>(ws + OFF_Y0, bn_g, bn_b, ws + OFF_CHSUM, ws + OFF_CHSQ,
                                    pool_w, pool_b, ws + OFF_DFLAT,
                                    YnT16, Sb16, STb16, ws + OFF_DENP);
    // fused gram + gramred + transformer + final + overlapped spmm
    xform<<<256, 512, 0, stream>>>(adj, STb16, Sb16, YnT16, ws + OFF_GPART, cls,
                                   ws + OFF_SS, ws + OFF_QKV,
                                   ln1_g, ln1_b, qkv_w, qkv_b, proj_w, proj_b,
                                   ln2_g, ln2_b, fc1_w, fc1_b, fc2_w, fc2_b,
                                   norm_g, norm_b, head_w, head_b,
                                   ws + OFF_DENP, ws + OFF_NUMP,
                                   (unsigned*)(ws + OFF_CTR), out);
}